// Round 1
// baseline (1166.101 us; speedup 1.0000x reference)
//
#include <hip/hip_runtime.h>
#include <hip/hip_bf16.h>
#include <type_traits>

#define LQ    900
#define BSZ   8
#define ROWS  (LQ*BSZ)        // 7200
#define CDIM  256
#define NH    8
#define DH    32
#define LVTOT 21824
#define VROWS (LVTOT*BSZ)     // 174592
#define DFF   2048

// ---------------- elementwise add (float4) ----------------
__global__ __launch_bounds__(256) void addvec_kernel(const float* __restrict__ a,
                                                     const float* __restrict__ b,
                                                     float* __restrict__ c, int n4) {
    int i = blockIdx.x * 256 + threadIdx.x;
    if (i < n4) {
        float4 x = reinterpret_cast<const float4*>(a)[i];
        float4 y = reinterpret_cast<const float4*>(b)[i];
        reinterpret_cast<float4*>(c)[i] = make_float4(x.x+y.x, x.y+y.y, x.z+y.z, x.w+y.w);
    }
}

// ---------------- generic tiled f32 GEMM: C = A@W + bias ----------------
// A: MxK row-major, W: KxN row-major. EPI: 0 none, 1 relu. OutT: float or bf16.
template<int EPI, typename OutT>
__global__ __launch_bounds__(256) void gemm_kernel(const float* __restrict__ A,
                                                   const float* __restrict__ W,
                                                   const float* __restrict__ bias,
                                                   OutT* __restrict__ C,
                                                   int M, int N, int K) {
    __shared__ float As[16][64];
    __shared__ float Bs[16][64];
    const int tid = threadIdx.x;
    const int m0 = blockIdx.y * 64;
    const int n0 = blockIdx.x * 64;
    const int tx = tid & 15, ty = tid >> 4;
    const int am = tid >> 2, ak4 = (tid & 3) * 4;   // A loads: 64 rows x 16 k
    const int bk = tid >> 4, bn4 = (tid & 15) * 4;  // B loads: 16 k x 64 n
    float acc[4][4] = {};
    for (int k0 = 0; k0 < K; k0 += 16) {
        {
            int row = m0 + am;
            float4 a = make_float4(0.f,0.f,0.f,0.f);
            if (row < M) a = *reinterpret_cast<const float4*>(&A[(size_t)row*K + k0 + ak4]);
            As[ak4+0][am] = a.x; As[ak4+1][am] = a.y; As[ak4+2][am] = a.z; As[ak4+3][am] = a.w;
        }
        {
            int col = n0 + bn4;
            float4 b = make_float4(0.f,0.f,0.f,0.f);
            if (col + 3 < N) b = *reinterpret_cast<const float4*>(&W[(size_t)(k0+bk)*N + col]);
            *reinterpret_cast<float4*>(&Bs[bk][bn4]) = b;
        }
        __syncthreads();
        #pragma unroll
        for (int kk = 0; kk < 16; ++kk) {
            float4 a4 = *reinterpret_cast<const float4*>(&As[kk][ty*4]);
            float4 b4 = *reinterpret_cast<const float4*>(&Bs[kk][tx*4]);
            float av[4] = {a4.x, a4.y, a4.z, a4.w};
            float bv[4] = {b4.x, b4.y, b4.z, b4.w};
            #pragma unroll
            for (int i = 0; i < 4; ++i)
                #pragma unroll
                for (int j = 0; j < 4; ++j)
                    acc[i][j] += av[i] * bv[j];
        }
        __syncthreads();
    }
    #pragma unroll
    for (int i = 0; i < 4; ++i) {
        int row = m0 + ty*4 + i;
        if (row >= M) continue;
        #pragma unroll
        for (int j = 0; j < 4; ++j) {
            int col = n0 + tx*4 + j;
            if (col >= N) continue;
            float v = acc[i][j] + bias[col];
            if (EPI == 1) v = fmaxf(v, 0.f);
            if constexpr (std::is_same<OutT, float>::value)
                C[(size_t)row*N + col] = v;
            else
                C[(size_t)row*N + col] = __float2bfloat16(v);
        }
    }
}

// ---------------- self-attention (online softmax) ----------------
// q,k,v laid out as (lq*B+b, h*32+d). One block = (b, h, 225-query tile).
__global__ __launch_bounds__(256) void attn_kernel(const float* __restrict__ q,
                                                   const float* __restrict__ k,
                                                   const float* __restrict__ v,
                                                   float* __restrict__ out) {
    __shared__ float Ks[64][32];
    __shared__ float Vs[64][32];
    const int bx = blockIdx.x;
    const int qt = bx & 3;
    const int h  = (bx >> 2) & 7;
    const int b  = bx >> 5;
    const int t  = threadIdx.x;
    const bool active = (t < 225);
    const int lq = qt * 225 + (active ? t : 224);
    const float scale = 0.1767766952966369f; // 1/sqrt(32)

    float qreg[32];
    {
        const float* qp = &q[((size_t)lq*BSZ + b)*CDIM + h*DH];
        #pragma unroll
        for (int i = 0; i < 8; ++i) {
            float4 t4 = reinterpret_cast<const float4*>(qp)[i];
            qreg[i*4+0] = t4.x*scale; qreg[i*4+1] = t4.y*scale;
            qreg[i*4+2] = t4.z*scale; qreg[i*4+3] = t4.w*scale;
        }
    }
    float m = -1e30f, l = 0.f;
    float acc[32];
    #pragma unroll
    for (int i = 0; i < 32; ++i) acc[i] = 0.f;

    for (int kc = 0; kc < LQ; kc += 64) {
        const int nk = min(64, LQ - kc);
        __syncthreads();
        for (int s = t; s < 512; s += 256) {
            int key = s >> 3, d4 = s & 7;
            int kidx = kc + key;
            float4 kv = make_float4(0.f,0.f,0.f,0.f), vv = kv;
            if (kidx < LQ) {
                size_t base = ((size_t)kidx*BSZ + b)*CDIM + h*DH + d4*4;
                kv = *reinterpret_cast<const float4*>(&k[base]);
                vv = *reinterpret_cast<const float4*>(&v[base]);
            }
            *reinterpret_cast<float4*>(&Ks[key][d4*4]) = kv;
            *reinterpret_cast<float4*>(&Vs[key][d4*4]) = vv;
        }
        __syncthreads();
        for (int kk = 0; kk < nk; ++kk) {
            float dot = 0.f;
            #pragma unroll
            for (int d2 = 0; d2 < 32; ++d2) dot += qreg[d2] * Ks[kk][d2];
            float nm = fmaxf(m, dot);
            float corr = __expf(m - nm);
            float p = __expf(dot - nm);
            l = l * corr + p;
            #pragma unroll
            for (int d2 = 0; d2 < 32; ++d2) acc[d2] = acc[d2]*corr + p*Vs[kk][d2];
            m = nm;
        }
    }
    if (active) {
        float inv = 1.f / l;
        float* op = &out[((size_t)lq*BSZ + b)*CDIM + h*DH];
        #pragma unroll
        for (int i = 0; i < 8; ++i) {
            float4 o4 = make_float4(acc[i*4]*inv, acc[i*4+1]*inv, acc[i*4+2]*inv, acc[i*4+3]*inv);
            reinterpret_cast<float4*>(op)[i] = o4;
        }
    }
}

// ---------------- fused residual + LayerNorm ----------------
// out = LN(xin + res); one wave (64 lanes) per 256-wide row, 4 rows/block.
__global__ __launch_bounds__(256) void ln_res_kernel(const float* __restrict__ xin,
                                                     const float* __restrict__ res,
                                                     const float* __restrict__ g,
                                                     const float* __restrict__ beta,
                                                     float* __restrict__ out) {
    const int row  = blockIdx.x * 4 + (threadIdx.x >> 6);
    const int lane = threadIdx.x & 63;
    const size_t base = (size_t)row * CDIM + lane * 4;
    float4 a = *reinterpret_cast<const float4*>(&xin[base]);
    float4 r = *reinterpret_cast<const float4*>(&res[base]);
    float x0 = a.x+r.x, x1 = a.y+r.y, x2 = a.z+r.z, x3 = a.w+r.w;
    float s = x0+x1+x2+x3;
    #pragma unroll
    for (int o = 1; o < 64; o <<= 1) s += __shfl_xor(s, o);
    float mean = s * (1.f/256.f);
    float d0 = x0-mean, d1 = x1-mean, d2 = x2-mean, d3 = x3-mean;
    float sq = d0*d0 + d1*d1 + d2*d2 + d3*d3;
    #pragma unroll
    for (int o = 1; o < 64; o <<= 1) sq += __shfl_xor(sq, o);
    float rs = rsqrtf(sq * (1.f/256.f) + 1e-5f);
    float4 gg = *reinterpret_cast<const float4*>(&g[lane*4]);
    float4 bb = *reinterpret_cast<const float4*>(&beta[lane*4]);
    float4 o4 = make_float4(d0*rs*gg.x+bb.x, d1*rs*gg.y+bb.y, d2*rs*gg.z+bb.z, d3*rs*gg.w+bb.w);
    *reinterpret_cast<float4*>(&out[base]) = o4;
}

// ---------------- softmax over 20 (deform attention weights) ----------------
__global__ __launch_bounds__(256) void softmax20_kernel(float* __restrict__ aw) {
    int item = blockIdx.x * 256 + threadIdx.x;
    if (item >= ROWS * NH) return;
    int row = item >> 3, h = item & 7;
    float* p = &aw[(size_t)row*160 + h*20];
    float mx = -1e30f;
    float e[20];
    #pragma unroll
    for (int j = 0; j < 20; ++j) mx = fmaxf(mx, p[j]);
    float sum = 0.f;
    #pragma unroll
    for (int j = 0; j < 20; ++j) { e[j] = __expf(p[j] - mx); sum += e[j]; }
    float inv = 1.f / sum;
    #pragma unroll
    for (int j = 0; j < 20; ++j) p[j] = e[j] * inv;
}

// ---------------- ms-deformable sampling ----------------
// value bf16 (lv*B+b, 256). 32 lanes per (b,q,h) group, 8 groups/block.
__global__ __launch_bounds__(256) void msdeform_kernel(const __hip_bfloat16* __restrict__ value,
                                                       const float* __restrict__ off,
                                                       const float* __restrict__ aw,
                                                       const float* __restrict__ refp,
                                                       float* __restrict__ samp) {
    const int gid = blockIdx.x * 8 + (threadIdx.x >> 5);
    const int d   = threadIdx.x & 31;
    const int h   = gid & 7;
    const int row = gid >> 3;       // lq*B + b
    const int b   = row & 7;        // B = 8
    const int HL[5] = {128, 64, 32, 16, 8};
    const int WL[5] = {128, 64, 32, 16, 8};
    const int SL[5] = {0, 16384, 20480, 21504, 21760};
    float acc = 0.f;
    #pragma unroll
    for (int l = 0; l < 5; ++l) {
        const float rx = refp[((size_t)row*5 + l)*2 + 0];
        const float ry = refp[((size_t)row*5 + l)*2 + 1];
        const float Wf = (float)WL[l], Hf = (float)HL[l];
        #pragma unroll
        for (int p = 0; p < 4; ++p) {
            const int oc = ((h*5 + l)*4 + p)*2;
            const float ox = off[(size_t)row*320 + oc];
            const float oy = off[(size_t)row*320 + oc + 1];
            const float a  = aw[(size_t)row*160 + h*20 + l*4 + p];
            const float x = (rx + ox / Wf) * Wf - 0.5f;
            const float y = (ry + oy / Hf) * Hf - 0.5f;
            const float x0f = floorf(x), y0f = floorf(y);
            const float fx = x - x0f, fy = y - y0f;
            const int x0 = (int)x0f, y0 = (int)y0f;
            const float w00 = (1.f-fx)*(1.f-fy), w10 = fx*(1.f-fy);
            const float w01 = (1.f-fx)*fy,       w11 = fx*fy;
            #pragma unroll
            for (int c = 0; c < 4; ++c) {
                const int dx = c & 1, dy = c >> 1;
                const int xc = x0 + dx, yc = y0 + dy;
                if (xc >= 0 && xc < WL[l] && yc >= 0 && yc < HL[l]) {
                    const float w = (c==0) ? w00 : (c==1) ? w10 : (c==2) ? w01 : w11;
                    const size_t vrow = (size_t)(SL[l] + yc*WL[l] + xc)*BSZ + b;
                    float vv = __bfloat162float(value[vrow*CDIM + h*DH + d]);
                    acc += a * w * vv;
                }
            }
        }
    }
    samp[(size_t)row*CDIM + h*DH + d] = acc;
}

// ---------------- launch ----------------
extern "C" void kernel_launch(void* const* d_in, const int* in_sizes, int n_in,
                              void* d_out, int out_size, void* d_ws, size_t ws_size,
                              hipStream_t stream) {
    (void)in_sizes; (void)n_in; (void)out_size; (void)ws_size;
    const float* tgt    = (const float*)d_in[0];
    const float* qpos   = (const float*)d_in[1];
    const float* refpts = (const float*)d_in[2];
    const float* memory = (const float*)d_in[3];
    const float* Wq  = (const float*)d_in[6];
    const float* Wk  = (const float*)d_in[7];
    const float* Wv  = (const float*)d_in[8];
    const float* Wo  = (const float*)d_in[9];
    const float* Woff= (const float*)d_in[10];
    const float* Watt= (const float*)d_in[11];
    const float* Wval= (const float*)d_in[12];
    const float* Wout= (const float*)d_in[13];
    const float* W1  = (const float*)d_in[14];
    const float* W2  = (const float*)d_in[15];
    const float* bq  = (const float*)d_in[16];
    const float* bk  = (const float*)d_in[17];
    const float* bv  = (const float*)d_in[18];
    const float* bo  = (const float*)d_in[19];
    const float* boff= (const float*)d_in[20];
    const float* batt= (const float*)d_in[21];
    const float* bval= (const float*)d_in[22];
    const float* bout= (const float*)d_in[23];
    const float* b1  = (const float*)d_in[24];
    const float* b2  = (const float*)d_in[25];
    const float* ln1g= (const float*)d_in[26];
    const float* ln1b= (const float*)d_in[27];
    const float* ln2g= (const float*)d_in[28];
    const float* ln2b= (const float*)d_in[29];
    const float* ln3g= (const float*)d_in[30];
    const float* ln3b= (const float*)d_in[31];
    float* out = (float*)d_out;

    char* ws = (char*)d_ws;
    const size_t RB = (size_t)ROWS * CDIM * 4;           // 7.37 MB
    float* tgt2 = (float*)(ws + 0*RB);
    float* tgt3 = (float*)(ws + 1*RB);
    float* qk   = (float*)(ws + 2*RB);   // also self-attn o
    float* qbuf = (float*)(ws + 3*RB);   // also qb
    float* kbuf = (float*)(ws + 4*RB);   // also samp
    float* vbuf = (float*)(ws + 5*RB);   // also cross-attn o
    float* abuf = (float*)(ws + 6*RB);   // attn_out, ffn_out
    float* offb = (float*)(ws + 7*RB);                        // 7200x320
    float* awb  = (float*)(ws + 7*RB + (size_t)ROWS*320*4);   // 7200x160
    char*  big  = ws + 7*RB + (size_t)ROWS*320*4 + (size_t)ROWS*160*4;
    __hip_bfloat16* valb = (__hip_bfloat16*)big;              // 174592x256 bf16 (89 MB)
    float* ffnh = (float*)big;                                // 7200x2048 f32 (59 MB, reuse)

    const int n4 = ROWS * CDIM / 4;
    const dim3 blk(256);

    // ---- stage 1: self-attention ----
    addvec_kernel<<<dim3((n4+255)/256), blk, 0, stream>>>(tgt, qpos, qk, n4);
    gemm_kernel<0,float><<<dim3(4,113), blk, 0, stream>>>(qk,  Wq, bq, qbuf, ROWS, CDIM, CDIM);
    gemm_kernel<0,float><<<dim3(4,113), blk, 0, stream>>>(qk,  Wk, bk, kbuf, ROWS, CDIM, CDIM);
    gemm_kernel<0,float><<<dim3(4,113), blk, 0, stream>>>(tgt, Wv, bv, vbuf, ROWS, CDIM, CDIM);
    attn_kernel<<<dim3(256), blk, 0, stream>>>(qbuf, kbuf, vbuf, abuf);
    gemm_kernel<0,float><<<dim3(4,113), blk, 0, stream>>>(abuf, Wo, bo, qk, ROWS, CDIM, CDIM);
    ln_res_kernel<<<dim3(ROWS/4), blk, 0, stream>>>(qk, tgt, ln2g, ln2b, tgt2);

    // ---- stage 2: deformable cross-attention ----
    gemm_kernel<0,__hip_bfloat16><<<dim3(4,VROWS/64), blk, 0, stream>>>(memory, Wval, bval, valb, VROWS, CDIM, CDIM);
    addvec_kernel<<<dim3((n4+255)/256), blk, 0, stream>>>(tgt2, qpos, qbuf, n4);
    gemm_kernel<0,float><<<dim3(5,113), blk, 0, stream>>>(qbuf, Woff, boff, offb, ROWS, 320, CDIM);
    gemm_kernel<0,float><<<dim3(3,113), blk, 0, stream>>>(qbuf, Watt, batt, awb,  ROWS, 160, CDIM);
    softmax20_kernel<<<dim3((ROWS*NH+255)/256), blk, 0, stream>>>(awb);
    msdeform_kernel<<<dim3(ROWS), blk, 0, stream>>>(valb, offb, awb, refpts, kbuf);
    gemm_kernel<0,float><<<dim3(4,113), blk, 0, stream>>>(kbuf, Wout, bout, vbuf, ROWS, CDIM, CDIM);
    ln_res_kernel<<<dim3(ROWS/4), blk, 0, stream>>>(vbuf, tgt2, ln1g, ln1b, tgt3);

    // ---- stage 3: FFN ----
    gemm_kernel<1,float><<<dim3(32,113), blk, 0, stream>>>(tgt3, W1, b1, ffnh, ROWS, DFF, CDIM);
    gemm_kernel<0,float><<<dim3(4,113), blk, 0, stream>>>(ffnh, W2, b2, abuf, ROWS, CDIM, DFF);
    ln_res_kernel<<<dim3(ROWS/4), blk, 0, stream>>>(abuf, tgt3, ln3g, ln3b, out);
}

// Round 2
// 766.988 us; speedup vs baseline: 1.5204x; 1.5204x over previous
//
#include <hip/hip_runtime.h>
#include <hip/hip_bf16.h>
#include <type_traits>

#define LQ    900
#define BSZ   8
#define ROWS  (LQ*BSZ)        // 7200
#define CDIM  256
#define NH    8
#define DH    32
#define LVTOT 21824
#define VROWS (LVTOT*BSZ)     // 174592
#define DFF   2048

typedef unsigned short u16;
typedef short short8 __attribute__((ext_vector_type(8)));
typedef float f32x4 __attribute__((ext_vector_type(4)));

__device__ __forceinline__ u16 f2bf(float f) {
    unsigned u = __float_as_uint(f);
    u += 0x7FFF + ((u >> 16) & 1);   // RNE
    return (u16)(u >> 16);
}

// ---------------- elementwise add (float4) ----------------
__global__ __launch_bounds__(256) void addvec_kernel(const float* __restrict__ a,
                                                     const float* __restrict__ b,
                                                     float* __restrict__ c, int n4) {
    int i = blockIdx.x * 256 + threadIdx.x;
    if (i < n4) {
        float4 x = reinterpret_cast<const float4*>(a)[i];
        float4 y = reinterpret_cast<const float4*>(b)[i];
        reinterpret_cast<float4*>(c)[i] = make_float4(x.x+y.x, x.y+y.y, x.z+y.z, x.w+y.w);
    }
}

// ---------------- weight transpose + cvt: W[K][N] f32 -> Wt[N][K] bf16 ----------------
// K, N multiples of 32 (true for all weights here).
__global__ __launch_bounds__(256) void wt_kernel(const float* __restrict__ W, u16* __restrict__ Wt,
                                                 int K, int N) {
    __shared__ float t[32][33];
    const int n0 = blockIdx.x * 32, k0 = blockIdx.y * 32;
    const int tx = threadIdx.x & 31, ty = threadIdx.x >> 5;
    #pragma unroll
    for (int r = ty; r < 32; r += 8)
        t[r][tx] = W[(size_t)(k0 + r) * N + n0 + tx];
    __syncthreads();
    #pragma unroll
    for (int r = ty; r < 32; r += 8)
        Wt[(size_t)(n0 + r) * K + k0 + tx] = f2bf(t[tx][r]);
}

// ---------------- bf16 MFMA GEMM: C = A @ W + bias ----------------
// A: MxK (f32 or bf16-bits), Wt: NxK bf16 (pre-transposed), C: MxN.
// 128x128 tile, BK=64, 4 waves (2x2), each wave 64x64 via 4x4 16x16x32 MFMAs.
// LDS layout: row-major [128][64] bf16, 16B chunk c of row r stored at chunk (c ^ (r&7)).
template<typename AT, int RELU, typename OutT>
__global__ __launch_bounds__(256) void gemm_mfma(const AT* __restrict__ A,
                                                 const u16* __restrict__ Wt,
                                                 const float* __restrict__ bias,
                                                 OutT* __restrict__ C,
                                                 int M, int N, int K) {
    __shared__ __align__(16) u16 As[128 * 64];
    __shared__ __align__(16) u16 Bs[128 * 64];
    const int tid = threadIdx.x;
    const int m0 = blockIdx.y * 128, n0 = blockIdx.x * 128;
    const int lane = tid & 63;
    const int wr = (tid >> 7) & 1, wc = (tid >> 6) & 1;
    const int lr = lane & 15, lg = lane >> 4;
    const int sr = tid >> 1;              // staging row 0..127
    const int sc = (tid & 1) * 4;         // staging chunk base (0 or 4)

    f32x4 acc[4][4] = {};

    for (int k0 = 0; k0 < K; k0 += 64) {
        // ---- stage A tile: row sr, k in [k0+sc*8, +32) ----
        {
            u16 tmp[32];
            const int grow = m0 + sr;
            if (grow < M) {
                if constexpr (std::is_same<AT, float>::value) {
                    const float4* src = reinterpret_cast<const float4*>(&A[(size_t)grow * K + k0 + sc * 8]);
                    #pragma unroll
                    for (int i = 0; i < 8; ++i) {
                        float4 v = src[i];
                        tmp[i*4+0] = f2bf(v.x); tmp[i*4+1] = f2bf(v.y);
                        tmp[i*4+2] = f2bf(v.z); tmp[i*4+3] = f2bf(v.w);
                    }
                } else {
                    const uint4* src = reinterpret_cast<const uint4*>(&A[(size_t)grow * K + k0 + sc * 8]);
                    #pragma unroll
                    for (int i = 0; i < 4; ++i)
                        *reinterpret_cast<uint4*>(&tmp[i*8]) = src[i];
                }
            } else {
                #pragma unroll
                for (int i = 0; i < 32; ++i) tmp[i] = 0;
            }
            #pragma unroll
            for (int c4 = 0; c4 < 4; ++c4) {
                const int c = sc + c4;
                *reinterpret_cast<uint4*>(&As[sr*64 + ((c ^ (sr & 7)) * 8)]) =
                    *reinterpret_cast<const uint4*>(&tmp[c4*8]);
            }
        }
        // ---- stage B tile from Wt (bf16, row = output col) ----
        {
            u16 tmp[32];
            const int gcol = n0 + sr;
            if (gcol < N) {
                const uint4* src = reinterpret_cast<const uint4*>(&Wt[(size_t)gcol * K + k0 + sc * 8]);
                #pragma unroll
                for (int i = 0; i < 4; ++i)
                    *reinterpret_cast<uint4*>(&tmp[i*8]) = src[i];
            } else {
                #pragma unroll
                for (int i = 0; i < 32; ++i) tmp[i] = 0;
            }
            #pragma unroll
            for (int c4 = 0; c4 < 4; ++c4) {
                const int c = sc + c4;
                *reinterpret_cast<uint4*>(&Bs[sr*64 + ((c ^ (sr & 7)) * 8)]) =
                    *reinterpret_cast<const uint4*>(&tmp[c4*8]);
            }
        }
        __syncthreads();
        #pragma unroll
        for (int h = 0; h < 2; ++h) {
            short8 af[4], bfr[4];
            #pragma unroll
            for (int i = 0; i < 4; ++i) {
                const int r = wr*64 + i*16 + lr;
                af[i] = *reinterpret_cast<const short8*>(&As[r*64 + (((h*4 + lg) ^ (r & 7)) * 8)]);
            }
            #pragma unroll
            for (int j = 0; j < 4; ++j) {
                const int r = wc*64 + j*16 + lr;
                bfr[j] = *reinterpret_cast<const short8*>(&Bs[r*64 + (((h*4 + lg) ^ (r & 7)) * 8)]);
            }
            #pragma unroll
            for (int i = 0; i < 4; ++i)
                #pragma unroll
                for (int j = 0; j < 4; ++j)
                    acc[i][j] = __builtin_amdgcn_mfma_f32_16x16x32_bf16(af[i], bfr[j], acc[i][j], 0, 0, 0);
        }
        __syncthreads();
    }
    // ---- epilogue: C/D layout col=lane&15, row=(lane>>4)*4+reg ----
    #pragma unroll
    for (int j = 0; j < 4; ++j) {
        const int col = n0 + wc*64 + j*16 + lr;
        if (col >= N) continue;
        const float bcol = bias[col];
        #pragma unroll
        for (int i = 0; i < 4; ++i) {
            #pragma unroll
            for (int r = 0; r < 4; ++r) {
                const int row = m0 + wr*64 + i*16 + lg*4 + r;
                if (row >= M) continue;
                float v = acc[i][j][r] + bcol;
                if (RELU) v = fmaxf(v, 0.f);
                if constexpr (std::is_same<OutT, float>::value)
                    C[(size_t)row * N + col] = v;
                else
                    C[(size_t)row * N + col] = f2bf(v);
            }
        }
    }
}

// ---------------- self-attention (online softmax) ----------------
__global__ __launch_bounds__(256) void attn_kernel(const float* __restrict__ q,
                                                   const float* __restrict__ k,
                                                   const float* __restrict__ v,
                                                   float* __restrict__ out) {
    __shared__ float Ks[64][32];
    __shared__ float Vs[64][32];
    const int bx = blockIdx.x;
    const int qt = bx & 3;
    const int h  = (bx >> 2) & 7;
    const int b  = bx >> 5;
    const int t  = threadIdx.x;
    const bool active = (t < 225);
    const int lq = qt * 225 + (active ? t : 224);
    const float scale = 0.1767766952966369f;

    float qreg[32];
    {
        const float* qp = &q[((size_t)lq*BSZ + b)*CDIM + h*DH];
        #pragma unroll
        for (int i = 0; i < 8; ++i) {
            float4 t4 = reinterpret_cast<const float4*>(qp)[i];
            qreg[i*4+0] = t4.x*scale; qreg[i*4+1] = t4.y*scale;
            qreg[i*4+2] = t4.z*scale; qreg[i*4+3] = t4.w*scale;
        }
    }
    float m = -1e30f, l = 0.f;
    float acc[32];
    #pragma unroll
    for (int i = 0; i < 32; ++i) acc[i] = 0.f;

    for (int kc = 0; kc < LQ; kc += 64) {
        const int nk = min(64, LQ - kc);
        __syncthreads();
        for (int s = t; s < 512; s += 256) {
            int key = s >> 3, d4 = s & 7;
            int kidx = kc + key;
            float4 kv = make_float4(0.f,0.f,0.f,0.f), vv = kv;
            if (kidx < LQ) {
                size_t base = ((size_t)kidx*BSZ + b)*CDIM + h*DH + d4*4;
                kv = *reinterpret_cast<const float4*>(&k[base]);
                vv = *reinterpret_cast<const float4*>(&v[base]);
            }
            *reinterpret_cast<float4*>(&Ks[key][d4*4]) = kv;
            *reinterpret_cast<float4*>(&Vs[key][d4*4]) = vv;
        }
        __syncthreads();
        for (int kk = 0; kk < nk; ++kk) {
            float dot = 0.f;
            #pragma unroll
            for (int d2 = 0; d2 < 32; ++d2) dot += qreg[d2] * Ks[kk][d2];
            float nm = fmaxf(m, dot);
            float corr = __expf(m - nm);
            float p = __expf(dot - nm);
            l = l * corr + p;
            #pragma unroll
            for (int d2 = 0; d2 < 32; ++d2) acc[d2] = acc[d2]*corr + p*Vs[kk][d2];
            m = nm;
        }
    }
    if (active) {
        float inv = 1.f / l;
        float* op = &out[((size_t)lq*BSZ + b)*CDIM + h*DH];
        #pragma unroll
        for (int i = 0; i < 8; ++i) {
            float4 o4 = make_float4(acc[i*4]*inv, acc[i*4+1]*inv, acc[i*4+2]*inv, acc[i*4+3]*inv);
            reinterpret_cast<float4*>(op)[i] = o4;
        }
    }
}

// ---------------- fused residual + LayerNorm ----------------
__global__ __launch_bounds__(256) void ln_res_kernel(const float* __restrict__ xin,
                                                     const float* __restrict__ res,
                                                     const float* __restrict__ g,
                                                     const float* __restrict__ beta,
                                                     float* __restrict__ out) {
    const int row  = blockIdx.x * 4 + (threadIdx.x >> 6);
    const int lane = threadIdx.x & 63;
    const size_t base = (size_t)row * CDIM + lane * 4;
    float4 a = *reinterpret_cast<const float4*>(&xin[base]);
    float4 r = *reinterpret_cast<const float4*>(&res[base]);
    float x0 = a.x+r.x, x1 = a.y+r.y, x2 = a.z+r.z, x3 = a.w+r.w;
    float s = x0+x1+x2+x3;
    #pragma unroll
    for (int o = 1; o < 64; o <<= 1) s += __shfl_xor(s, o);
    float mean = s * (1.f/256.f);
    float d0 = x0-mean, d1 = x1-mean, d2 = x2-mean, d3 = x3-mean;
    float sq = d0*d0 + d1*d1 + d2*d2 + d3*d3;
    #pragma unroll
    for (int o = 1; o < 64; o <<= 1) sq += __shfl_xor(sq, o);
    float rs = rsqrtf(sq * (1.f/256.f) + 1e-5f);
    float4 gg = *reinterpret_cast<const float4*>(&g[lane*4]);
    float4 bb = *reinterpret_cast<const float4*>(&beta[lane*4]);
    float4 o4 = make_float4(d0*rs*gg.x+bb.x, d1*rs*gg.y+bb.y, d2*rs*gg.z+bb.z, d3*rs*gg.w+bb.w);
    *reinterpret_cast<float4*>(&out[base]) = o4;
}

// ---------------- softmax over 20 ----------------
__global__ __launch_bounds__(256) void softmax20_kernel(float* __restrict__ aw) {
    int item = blockIdx.x * 256 + threadIdx.x;
    if (item >= ROWS * NH) return;
    int row = item >> 3, h = item & 7;
    float* p = &aw[(size_t)row*160 + h*20];
    float mx = -1e30f;
    float e[20];
    #pragma unroll
    for (int j = 0; j < 20; ++j) mx = fmaxf(mx, p[j]);
    float sum = 0.f;
    #pragma unroll
    for (int j = 0; j < 20; ++j) { e[j] = __expf(p[j] - mx); sum += e[j]; }
    float inv = 1.f / sum;
    #pragma unroll
    for (int j = 0; j < 20; ++j) p[j] = e[j] * inv;
}

// ---------------- ms-deformable sampling ----------------
__global__ __launch_bounds__(256) void msdeform_kernel(const __hip_bfloat16* __restrict__ value,
                                                       const float* __restrict__ off,
                                                       const float* __restrict__ aw,
                                                       const float* __restrict__ refp,
                                                       float* __restrict__ samp) {
    const int gid = blockIdx.x * 8 + (threadIdx.x >> 5);
    const int d   = threadIdx.x & 31;
    const int h   = gid & 7;
    const int row = gid >> 3;
    const int b   = row & 7;
    const int HL[5] = {128, 64, 32, 16, 8};
    const int WL[5] = {128, 64, 32, 16, 8};
    const int SL[5] = {0, 16384, 20480, 21504, 21760};
    float acc = 0.f;
    #pragma unroll
    for (int l = 0; l < 5; ++l) {
        const float rx = refp[((size_t)row*5 + l)*2 + 0];
        const float ry = refp[((size_t)row*5 + l)*2 + 1];
        const float Wf = (float)WL[l], Hf = (float)HL[l];
        #pragma unroll
        for (int p = 0; p < 4; ++p) {
            const int oc = ((h*5 + l)*4 + p)*2;
            const float ox = off[(size_t)row*320 + oc];
            const float oy = off[(size_t)row*320 + oc + 1];
            const float a  = aw[(size_t)row*160 + h*20 + l*4 + p];
            const float x = (rx + ox / Wf) * Wf - 0.5f;
            const float y = (ry + oy / Hf) * Hf - 0.5f;
            const float x0f = floorf(x), y0f = floorf(y);
            const float fx = x - x0f, fy = y - y0f;
            const int x0 = (int)x0f, y0 = (int)y0f;
            const float w00 = (1.f-fx)*(1.f-fy), w10 = fx*(1.f-fy);
            const float w01 = (1.f-fx)*fy,       w11 = fx*fy;
            #pragma unroll
            for (int c = 0; c < 4; ++c) {
                const int dx = c & 1, dy = c >> 1;
                const int xc = x0 + dx, yc = y0 + dy;
                if (xc >= 0 && xc < WL[l] && yc >= 0 && yc < HL[l]) {
                    const float w = (c==0) ? w00 : (c==1) ? w10 : (c==2) ? w01 : w11;
                    const size_t vrow = (size_t)(SL[l] + yc*WL[l] + xc)*BSZ + b;
                    float vv = __bfloat162float(value[vrow*CDIM + h*DH + d]);
                    acc += a * w * vv;
                }
            }
        }
    }
    samp[(size_t)row*CDIM + h*DH + d] = acc;
}

// ---------------- launch ----------------
extern "C" void kernel_launch(void* const* d_in, const int* in_sizes, int n_in,
                              void* d_out, int out_size, void* d_ws, size_t ws_size,
                              hipStream_t stream) {
    (void)in_sizes; (void)n_in; (void)out_size; (void)ws_size;
    const float* tgt    = (const float*)d_in[0];
    const float* qpos   = (const float*)d_in[1];
    const float* refpts = (const float*)d_in[2];
    const float* memory = (const float*)d_in[3];
    const float* Wq  = (const float*)d_in[6];
    const float* Wk  = (const float*)d_in[7];
    const float* Wv  = (const float*)d_in[8];
    const float* Wo  = (const float*)d_in[9];
    const float* Woff= (const float*)d_in[10];
    const float* Watt= (const float*)d_in[11];
    const float* Wval= (const float*)d_in[12];
    const float* Wout= (const float*)d_in[13];
    const float* W1  = (const float*)d_in[14];
    const float* W2  = (const float*)d_in[15];
    const float* bq  = (const float*)d_in[16];
    const float* bk  = (const float*)d_in[17];
    const float* bv  = (const float*)d_in[18];
    const float* bo  = (const float*)d_in[19];
    const float* boff= (const float*)d_in[20];
    const float* batt= (const float*)d_in[21];
    const float* bval= (const float*)d_in[22];
    const float* bout= (const float*)d_in[23];
    const float* b1  = (const float*)d_in[24];
    const float* b2  = (const float*)d_in[25];
    const float* ln1g= (const float*)d_in[26];
    const float* ln1b= (const float*)d_in[27];
    const float* ln2g= (const float*)d_in[28];
    const float* ln2b= (const float*)d_in[29];
    const float* ln3g= (const float*)d_in[30];
    const float* ln3b= (const float*)d_in[31];
    float* out = (float*)d_out;

    char* ws = (char*)d_ws;
    const size_t RB = (size_t)ROWS * CDIM * 4;           // 7.37 MB
    float* tgt2 = (float*)(ws + 0*RB);
    float* tgt3 = (float*)(ws + 1*RB);
    float* qk   = (float*)(ws + 2*RB);
    float* qbuf = (float*)(ws + 3*RB);
    float* kbuf = (float*)(ws + 4*RB);   // also samp
    float* vbuf = (float*)(ws + 5*RB);
    float* abuf = (float*)(ws + 6*RB);
    float* offb = (float*)(ws + 7*RB);                        // 7200x320
    float* awb  = (float*)(ws + 7*RB + (size_t)ROWS*320*4);   // 7200x160
    char*  wsm  = ws + 7*RB + (size_t)ROWS*320*4 + (size_t)ROWS*160*4;
    u16* WqT   = (u16*)(wsm + 0*131072);
    u16* WkT   = (u16*)(wsm + 1*131072);
    u16* WvT   = (u16*)(wsm + 2*131072);
    u16* WoT   = (u16*)(wsm + 3*131072);
    u16* WvalT = (u16*)(wsm + 4*131072);
    u16* WoutT = (u16*)(wsm + 5*131072);
    u16* WoffT = (u16*)(wsm + 6*131072);                 // 320x256x2 = 163840
    u16* WattT = (u16*)(wsm + 6*131072 + 163840);        // 160x256x2 = 81920
    char* big  = wsm + 6*131072 + 163840 + 81920;
    u16* valb  = (u16*)big;                              // 174592x256 bf16 (89 MB)
    u16* W1T   = (u16*)big;                              // 2048x256 bf16 (after msdeform)
    u16* W2T   = (u16*)(big + 1048576);                  // 256x2048 bf16
    u16* ffnh  = (u16*)(big + 2097152);                  // 7200x2048 bf16

    const int n4 = ROWS * CDIM / 4;
    const dim3 blk(256);

    // ---- weight transposes (f32 [K][N] -> bf16 [N][K]) ----
    wt_kernel<<<dim3(8,8),  blk, 0, stream>>>(Wq,   WqT,   CDIM, CDIM);
    wt_kernel<<<dim3(8,8),  blk, 0, stream>>>(Wk,   WkT,   CDIM, CDIM);
    wt_kernel<<<dim3(8,8),  blk, 0, stream>>>(Wv,   WvT,   CDIM, CDIM);
    wt_kernel<<<dim3(8,8),  blk, 0, stream>>>(Wo,   WoT,   CDIM, CDIM);
    wt_kernel<<<dim3(8,8),  blk, 0, stream>>>(Wval, WvalT, CDIM, CDIM);
    wt_kernel<<<dim3(8,8),  blk, 0, stream>>>(Wout, WoutT, CDIM, CDIM);
    wt_kernel<<<dim3(10,8), blk, 0, stream>>>(Woff, WoffT, CDIM, 320);
    wt_kernel<<<dim3(5,8),  blk, 0, stream>>>(Watt, WattT, CDIM, 160);

    // ---- stage 1: self-attention ----
    addvec_kernel<<<dim3((n4+255)/256), blk, 0, stream>>>(tgt, qpos, qk, n4);
    gemm_mfma<float,0,float><<<dim3(2,57), blk, 0, stream>>>(qk,  WqT, bq, qbuf, ROWS, CDIM, CDIM);
    gemm_mfma<float,0,float><<<dim3(2,57), blk, 0, stream>>>(qk,  WkT, bk, kbuf, ROWS, CDIM, CDIM);
    gemm_mfma<float,0,float><<<dim3(2,57), blk, 0, stream>>>(tgt, WvT, bv, vbuf, ROWS, CDIM, CDIM);
    attn_kernel<<<dim3(256), blk, 0, stream>>>(qbuf, kbuf, vbuf, abuf);
    gemm_mfma<float,0,float><<<dim3(2,57), blk, 0, stream>>>(abuf, WoT, bo, qk, ROWS, CDIM, CDIM);
    ln_res_kernel<<<dim3(ROWS/4), blk, 0, stream>>>(qk, tgt, ln2g, ln2b, tgt2);

    // ---- stage 2: deformable cross-attention ----
    gemm_mfma<float,0,u16><<<dim3(2,1364), blk, 0, stream>>>(memory, WvalT, bval, valb, VROWS, CDIM, CDIM);
    addvec_kernel<<<dim3((n4+255)/256), blk, 0, stream>>>(tgt2, qpos, qbuf, n4);
    gemm_mfma<float,0,float><<<dim3(3,57), blk, 0, stream>>>(qbuf, WoffT, boff, offb, ROWS, 320, CDIM);
    gemm_mfma<float,0,float><<<dim3(2,57), blk, 0, stream>>>(qbuf, WattT, batt, awb,  ROWS, 160, CDIM);
    softmax20_kernel<<<dim3((ROWS*NH+255)/256), blk, 0, stream>>>(awb);
    msdeform_kernel<<<dim3(ROWS), blk, 0, stream>>>((const __hip_bfloat16*)valb, offb, awb, refpts, kbuf);
    gemm_mfma<float,0,float><<<dim3(2,57), blk, 0, stream>>>(kbuf, WoutT, bout, vbuf, ROWS, CDIM, CDIM);
    ln_res_kernel<<<dim3(ROWS/4), blk, 0, stream>>>(vbuf, tgt2, ln1g, ln1b, tgt3);

    // ---- stage 3: FFN (W1T/W2T alias the dead valb region) ----
    wt_kernel<<<dim3(64,8), blk, 0, stream>>>(W1, W1T, CDIM, DFF);
    wt_kernel<<<dim3(8,64), blk, 0, stream>>>(W2, W2T, DFF, CDIM);
    gemm_mfma<float,1,u16><<<dim3(16,57), blk, 0, stream>>>(tgt3, W1T, b1, ffnh, ROWS, DFF, CDIM);
    gemm_mfma<u16,0,float><<<dim3(2,57),  blk, 0, stream>>>(ffnh, W2T, b2, abuf, ROWS, CDIM, DFF);
    ln_res_kernel<<<dim3(ROWS/4), blk, 0, stream>>>(abuf, tgt3, ln3g, ln3b, out);
}

// Round 3
// 553.523 us; speedup vs baseline: 2.1067x; 1.3856x over previous
//
#include <hip/hip_runtime.h>
#include <hip/hip_bf16.h>
#include <type_traits>

#define LQ    900
#define BSZ   8
#define ROWS  (LQ*BSZ)        // 7200
#define CDIM  256
#define NH    8
#define DH    32
#define LVTOT 21824
#define VROWS (LVTOT*BSZ)     // 174592
#define DFF   2048

typedef unsigned short u16;
typedef short short8 __attribute__((ext_vector_type(8)));
typedef float f32x4 __attribute__((ext_vector_type(4)));

__device__ __forceinline__ u16 f2bf(float f) {
    unsigned u = __float_as_uint(f);
    u += 0x7FFF + ((u >> 16) & 1);   // RNE
    return (u16)(u >> 16);
}

// ---------------- elementwise add (float4) ----------------
__global__ __launch_bounds__(256) void addvec_kernel(const float* __restrict__ a,
                                                     const float* __restrict__ b,
                                                     float* __restrict__ c, int n4) {
    int i = blockIdx.x * 256 + threadIdx.x;
    if (i < n4) {
        float4 x = reinterpret_cast<const float4*>(a)[i];
        float4 y = reinterpret_cast<const float4*>(b)[i];
        reinterpret_cast<float4*>(c)[i] = make_float4(x.x+y.x, x.y+y.y, x.z+y.z, x.w+y.w);
    }
}

// ---------------- weight transpose + cvt: W[K][N] f32 -> Wt[N][K] bf16 ----------------
__global__ __launch_bounds__(256) void wt_kernel(const float* __restrict__ W, u16* __restrict__ Wt,
                                                 int K, int N) {
    __shared__ float t[32][33];
    const int n0 = blockIdx.x * 32, k0 = blockIdx.y * 32;
    const int tx = threadIdx.x & 31, ty = threadIdx.x >> 5;
    #pragma unroll
    for (int r = ty; r < 32; r += 8)
        t[r][tx] = W[(size_t)(k0 + r) * N + n0 + tx];
    __syncthreads();
    #pragma unroll
    for (int r = ty; r < 32; r += 8)
        Wt[(size_t)(n0 + r) * K + k0 + tx] = f2bf(t[tx][r]);
}

// ---------------- bf16 MFMA GEMM: C = A @ W + bias ----------------
template<typename AT, int RELU, typename OutT>
__global__ __launch_bounds__(256) void gemm_mfma(const AT* __restrict__ A,
                                                 const u16* __restrict__ Wt,
                                                 const float* __restrict__ bias,
                                                 OutT* __restrict__ C,
                                                 int M, int N, int K) {
    __shared__ __align__(16) u16 As[128 * 64];
    __shared__ __align__(16) u16 Bs[128 * 64];
    const int tid = threadIdx.x;
    const int m0 = blockIdx.y * 128, n0 = blockIdx.x * 128;
    const int lane = tid & 63;
    const int wr = (tid >> 7) & 1, wc = (tid >> 6) & 1;
    const int lr = lane & 15, lg = lane >> 4;
    const int sr = tid >> 1;
    const int sc = (tid & 1) * 4;

    f32x4 acc[4][4] = {};

    for (int k0 = 0; k0 < K; k0 += 64) {
        {
            u16 tmp[32];
            const int grow = m0 + sr;
            if (grow < M) {
                if constexpr (std::is_same<AT, float>::value) {
                    const float4* src = reinterpret_cast<const float4*>(&A[(size_t)grow * K + k0 + sc * 8]);
                    #pragma unroll
                    for (int i = 0; i < 8; ++i) {
                        float4 v = src[i];
                        tmp[i*4+0] = f2bf(v.x); tmp[i*4+1] = f2bf(v.y);
                        tmp[i*4+2] = f2bf(v.z); tmp[i*4+3] = f2bf(v.w);
                    }
                } else {
                    const uint4* src = reinterpret_cast<const uint4*>(&A[(size_t)grow * K + k0 + sc * 8]);
                    #pragma unroll
                    for (int i = 0; i < 4; ++i)
                        *reinterpret_cast<uint4*>(&tmp[i*8]) = src[i];
                }
            } else {
                #pragma unroll
                for (int i = 0; i < 32; ++i) tmp[i] = 0;
            }
            #pragma unroll
            for (int c4 = 0; c4 < 4; ++c4) {
                const int c = sc + c4;
                *reinterpret_cast<uint4*>(&As[sr*64 + ((c ^ (sr & 7)) * 8)]) =
                    *reinterpret_cast<const uint4*>(&tmp[c4*8]);
            }
        }
        {
            u16 tmp[32];
            const int gcol = n0 + sr;
            if (gcol < N) {
                const uint4* src = reinterpret_cast<const uint4*>(&Wt[(size_t)gcol * K + k0 + sc * 8]);
                #pragma unroll
                for (int i = 0; i < 4; ++i)
                    *reinterpret_cast<uint4*>(&tmp[i*8]) = src[i];
            } else {
                #pragma unroll
                for (int i = 0; i < 32; ++i) tmp[i] = 0;
            }
            #pragma unroll
            for (int c4 = 0; c4 < 4; ++c4) {
                const int c = sc + c4;
                *reinterpret_cast<uint4*>(&Bs[sr*64 + ((c ^ (sr & 7)) * 8)]) =
                    *reinterpret_cast<const uint4*>(&tmp[c4*8]);
            }
        }
        __syncthreads();
        #pragma unroll
        for (int h = 0; h < 2; ++h) {
            short8 af[4], bfr[4];
            #pragma unroll
            for (int i = 0; i < 4; ++i) {
                const int r = wr*64 + i*16 + lr;
                af[i] = *reinterpret_cast<const short8*>(&As[r*64 + (((h*4 + lg) ^ (r & 7)) * 8)]);
            }
            #pragma unroll
            for (int j = 0; j < 4; ++j) {
                const int r = wc*64 + j*16 + lr;
                bfr[j] = *reinterpret_cast<const short8*>(&Bs[r*64 + (((h*4 + lg) ^ (r & 7)) * 8)]);
            }
            #pragma unroll
            for (int i = 0; i < 4; ++i)
                #pragma unroll
                for (int j = 0; j < 4; ++j)
                    acc[i][j] = __builtin_amdgcn_mfma_f32_16x16x32_bf16(af[i], bfr[j], acc[i][j], 0, 0, 0);
        }
        __syncthreads();
    }
    #pragma unroll
    for (int j = 0; j < 4; ++j) {
        const int col = n0 + wc*64 + j*16 + lr;
        if (col >= N) continue;
        const float bcol = bias[col];
        #pragma unroll
        for (int i = 0; i < 4; ++i) {
            #pragma unroll
            for (int r = 0; r < 4; ++r) {
                const int row = m0 + wr*64 + i*16 + lg*4 + r;
                if (row >= M) continue;
                float v = acc[i][j][r] + bcol;
                if (RELU) v = fmaxf(v, 0.f);
                if constexpr (std::is_same<OutT, float>::value)
                    C[(size_t)row * N + col] = v;
                else
                    C[(size_t)row * N + col] = f2bf(v);
            }
        }
    }
}

// ---------------- MFMA flash self-attention ----------------
// q,k,v f32 (lq*B+b, h*32+d). Block = (b,h,qt): 128 queries, 4 waves x 32 q.
// S^T = mfma(K,Q) so each lane's column is a query and P is lane-local for PV.
__global__ __launch_bounds__(256) void attn_mfma_kernel(const float* __restrict__ q,
                                                        const float* __restrict__ k,
                                                        const float* __restrict__ v,
                                                        float* __restrict__ out) {
    __shared__ __align__(16) u16 Ks[64*32];   // [key][32 d], 16B chunk c stored at c^((key>>1)&3)
    __shared__ __align__(16) u16 Vt[32*64];   // [dh][64 key], 16B chunk c stored at c^(dh&7)
    const int bx = blockIdx.x;
    const int qt = bx & 7, h = (bx >> 3) & 7, b = bx >> 6;
    const int tid = threadIdx.x;
    const int w = tid >> 6, lane = tid & 63;
    const int lr = lane & 15, lg = lane >> 4;
    const int m0 = qt*128 + w*32;
    const float scale = 0.1767766952966369f;

    // Q B-fragments (col = query = lr + j*16, k-elem = lg*8+e), scale folded in
    short8 qf[2];
    #pragma unroll
    for (int j = 0; j < 2; ++j) {
        int lq = m0 + j*16 + lr; if (lq > LQ-1) lq = LQ-1;
        const float* qp = &q[((size_t)lq*BSZ + b)*CDIM + h*DH + lg*8];
        float4 a = *reinterpret_cast<const float4*>(qp);
        float4 c = *reinterpret_cast<const float4*>(qp + 4);
        u16 t[8] = { f2bf(a.x*scale), f2bf(a.y*scale), f2bf(a.z*scale), f2bf(a.w*scale),
                     f2bf(c.x*scale), f2bf(c.y*scale), f2bf(c.z*scale), f2bf(c.w*scale) };
        qf[j] = *reinterpret_cast<short8*>(t);
    }

    f32x4 o00 = {}, o01 = {}, o10 = {}, o11 = {};   // o[dh-frag][q-frag]
    float m[2] = {-1e30f, -1e30f}, l[2] = {0.f, 0.f};
    const f32x4 zero = {};

    for (int kt = 0; kt < 15; ++kt) {
        __syncthreads();
        // ---- stage K (row-major swz) and V (transposed swz) ----
        {
            const int key = tid >> 2, c = tid & 3;
            int kg = kt*64 + key; if (kg > LQ-1) kg = LQ-1;
            const size_t base = ((size_t)kg*BSZ + b)*CDIM + h*DH + c*8;
            float4 k0 = *reinterpret_cast<const float4*>(&k[base]);
            float4 k1 = *reinterpret_cast<const float4*>(&k[base+4]);
            float4 v0 = *reinterpret_cast<const float4*>(&v[base]);
            float4 v1 = *reinterpret_cast<const float4*>(&v[base+4]);
            u16 kb[8] = { f2bf(k0.x), f2bf(k0.y), f2bf(k0.z), f2bf(k0.w),
                          f2bf(k1.x), f2bf(k1.y), f2bf(k1.z), f2bf(k1.w) };
            *reinterpret_cast<short8*>(&Ks[key*32 + ((c ^ ((key>>1)&3)) * 8)]) =
                *reinterpret_cast<short8*>(kb);
            float vv[8] = { v0.x, v0.y, v0.z, v0.w, v1.x, v1.y, v1.z, v1.w };
            #pragma unroll
            for (int e = 0; e < 8; ++e) {
                const int dh = c*8 + e;
                Vt[dh*64 + (((key>>3) ^ (dh&7)) * 8) + (key&7)] = f2bf(vv[e]);
            }
        }
        __syncthreads();

        // ---- S^T = K @ Q^T : rows=keys (4 frags), cols=queries (2 frags) ----
        f32x4 s[4][2];
        #pragma unroll
        for (int i = 0; i < 4; ++i) {
            const int key = i*16 + lr;
            short8 kf = *reinterpret_cast<const short8*>(&Ks[key*32 + ((lg ^ ((key>>1)&3)) * 8)]);
            s[i][0] = __builtin_amdgcn_mfma_f32_16x16x32_bf16(kf, qf[0], zero, 0, 0, 0);
            s[i][1] = __builtin_amdgcn_mfma_f32_16x16x32_bf16(kf, qf[1], zero, 0, 0, 0);
        }
        // ---- mask invalid keys (key = kt*64 + i*16 + lg*4 + r) ----
        const int lim = LQ - kt*64 - lg*4;
        #pragma unroll
        for (int i = 0; i < 4; ++i)
            #pragma unroll
            for (int r = 0; r < 4; ++r)
                if (i*16 + r >= lim) { s[i][0][r] = -1e30f; s[i][1][r] = -1e30f; }

        // ---- online softmax per query column (j selects 16 queries) ----
        #pragma unroll
        for (int j = 0; j < 2; ++j) {
            float mx = -1e30f;
            #pragma unroll
            for (int i = 0; i < 4; ++i)
                #pragma unroll
                for (int r = 0; r < 4; ++r) mx = fmaxf(mx, s[i][j][r]);
            mx = fmaxf(mx, __shfl_xor(mx, 16));
            mx = fmaxf(mx, __shfl_xor(mx, 32));
            const float mn = fmaxf(m[j], mx);
            const float corr = __expf(m[j] - mn);
            float sum = 0.f;
            #pragma unroll
            for (int i = 0; i < 4; ++i)
                #pragma unroll
                for (int r = 0; r < 4; ++r) {
                    float p = __expf(s[i][j][r] - mn);
                    s[i][j][r] = p;
                    sum += p;
                }
            sum += __shfl_xor(sum, 16);
            sum += __shfl_xor(sum, 32);
            l[j] = l[j]*corr + sum;
            m[j] = mn;
            if (j == 0) { o00 *= corr; o10 *= corr; }
            else        { o01 *= corr; o11 *= corr; }
        }

        // ---- pack P^T B-frags: elem e<4 -> key kh*32+lg*4+e, e>=4 -> +16 ----
        short8 pb[2][2];
        #pragma unroll
        for (int kh = 0; kh < 2; ++kh)
            #pragma unroll
            for (int j = 0; j < 2; ++j) {
                u16 t[8];
                #pragma unroll
                for (int e = 0; e < 4; ++e) {
                    t[e]   = f2bf(s[2*kh][j][e]);
                    t[e+4] = f2bf(s[2*kh+1][j][e]);
                }
                pb[kh][j] = *reinterpret_cast<short8*>(t);
            }

        // ---- PV: O^T[dh][q] += V^T-frag x P^T-frag (same k-bijection) ----
        #pragma unroll
        for (int ip = 0; ip < 2; ++ip) {
            const int dh = ip*16 + lr;
            #pragma unroll
            for (int kh = 0; kh < 2; ++kh) {
                u16 t[8];
                const int c0 = (kh*4 + (lg>>1)) ^ (dh&7);
                const int c1 = (kh*4 + 2 + (lg>>1)) ^ (dh&7);
                *reinterpret_cast<uint2*>(&t[0]) =
                    *reinterpret_cast<const uint2*>(&Vt[dh*64 + c0*8 + (lg&1)*4]);
                *reinterpret_cast<uint2*>(&t[4]) =
                    *reinterpret_cast<const uint2*>(&Vt[dh*64 + c1*8 + (lg&1)*4]);
                short8 vf = *reinterpret_cast<short8*>(t);
                if (ip == 0) {
                    o00 = __builtin_amdgcn_mfma_f32_16x16x32_bf16(vf, pb[kh][0], o00, 0, 0, 0);
                    o01 = __builtin_amdgcn_mfma_f32_16x16x32_bf16(vf, pb[kh][1], o01, 0, 0, 0);
                } else {
                    o10 = __builtin_amdgcn_mfma_f32_16x16x32_bf16(vf, pb[kh][0], o10, 0, 0, 0);
                    o11 = __builtin_amdgcn_mfma_f32_16x16x32_bf16(vf, pb[kh][1], o11, 0, 0, 0);
                }
            }
        }
    }

    // ---- store O (O^T frag: col=query=lr+j*16, row=dh=ip*16+lg*4+r) ----
    #pragma unroll
    for (int j = 0; j < 2; ++j) {
        const int lq = m0 + j*16 + lr;
        if (lq >= LQ) continue;
        const float inv = 1.f / l[j];
        float* op = &out[((size_t)lq*BSZ + b)*CDIM + h*DH];
        #pragma unroll
        for (int r = 0; r < 4; ++r) {
            const f32x4& a0 = (j == 0) ? o00 : o01;
            const f32x4& a1 = (j == 0) ? o10 : o11;
            op[lg*4 + r]      = a0[r] * inv;
            op[16 + lg*4 + r] = a1[r] * inv;
        }
    }
}

// ---------------- fused residual + LayerNorm ----------------
__global__ __launch_bounds__(256) void ln_res_kernel(const float* __restrict__ xin,
                                                     const float* __restrict__ res,
                                                     const float* __restrict__ g,
                                                     const float* __restrict__ beta,
                                                     float* __restrict__ out) {
    const int row  = blockIdx.x * 4 + (threadIdx.x >> 6);
    const int lane = threadIdx.x & 63;
    const size_t base = (size_t)row * CDIM + lane * 4;
    float4 a = *reinterpret_cast<const float4*>(&xin[base]);
    float4 r = *reinterpret_cast<const float4*>(&res[base]);
    float x0 = a.x+r.x, x1 = a.y+r.y, x2 = a.z+r.z, x3 = a.w+r.w;
    float s = x0+x1+x2+x3;
    #pragma unroll
    for (int o = 1; o < 64; o <<= 1) s += __shfl_xor(s, o);
    float mean = s * (1.f/256.f);
    float d0 = x0-mean, d1 = x1-mean, d2 = x2-mean, d3 = x3-mean;
    float sq = d0*d0 + d1*d1 + d2*d2 + d3*d3;
    #pragma unroll
    for (int o = 1; o < 64; o <<= 1) sq += __shfl_xor(sq, o);
    float rs = rsqrtf(sq * (1.f/256.f) + 1e-5f);
    float4 gg = *reinterpret_cast<const float4*>(&g[lane*4]);
    float4 bb = *reinterpret_cast<const float4*>(&beta[lane*4]);
    float4 o4 = make_float4(d0*rs*gg.x+bb.x, d1*rs*gg.y+bb.y, d2*rs*gg.z+bb.z, d3*rs*gg.w+bb.w);
    *reinterpret_cast<float4*>(&out[base]) = o4;
}

// ---------------- softmax over 20 ----------------
__global__ __launch_bounds__(256) void softmax20_kernel(float* __restrict__ aw) {
    int item = blockIdx.x * 256 + threadIdx.x;
    if (item >= ROWS * NH) return;
    int row = item >> 3, h = item & 7;
    float* p = &aw[(size_t)row*160 + h*20];
    float mx = -1e30f;
    float e[20];
    #pragma unroll
    for (int j = 0; j < 20; ++j) mx = fmaxf(mx, p[j]);
    float sum = 0.f;
    #pragma unroll
    for (int j = 0; j < 20; ++j) { e[j] = __expf(p[j] - mx); sum += e[j]; }
    float inv = 1.f / sum;
    #pragma unroll
    for (int j = 0; j < 20; ++j) p[j] = e[j] * inv;
}

// ---------------- ms-deformable sampling ----------------
__global__ __launch_bounds__(256) void msdeform_kernel(const __hip_bfloat16* __restrict__ value,
                                                       const float* __restrict__ off,
                                                       const float* __restrict__ aw,
                                                       const float* __restrict__ refp,
                                                       float* __restrict__ samp) {
    const int gid = blockIdx.x * 8 + (threadIdx.x >> 5);
    const int d   = threadIdx.x & 31;
    const int h   = gid & 7;
    const int row = gid >> 3;
    const int b   = row & 7;
    const int HL[5] = {128, 64, 32, 16, 8};
    const int WL[5] = {128, 64, 32, 16, 8};
    const int SL[5] = {0, 16384, 20480, 21504, 21760};
    float acc = 0.f;
    #pragma unroll
    for (int l = 0; l < 5; ++l) {
        const float rx = refp[((size_t)row*5 + l)*2 + 0];
        const float ry = refp[((size_t)row*5 + l)*2 + 1];
        const float Wf = (float)WL[l], Hf = (float)HL[l];
        #pragma unroll
        for (int p = 0; p < 4; ++p) {
            const int oc = ((h*5 + l)*4 + p)*2;
            const float ox = off[(size_t)row*320 + oc];
            const float oy = off[(size_t)row*320 + oc + 1];
            const float a  = aw[(size_t)row*160 + h*20 + l*4 + p];
            const float x = (rx + ox / Wf) * Wf - 0.5f;
            const float y = (ry + oy / Hf) * Hf - 0.5f;
            const float x0f = floorf(x), y0f = floorf(y);
            const float fx = x - x0f, fy = y - y0f;
            const int x0 = (int)x0f, y0 = (int)y0f;
            const float w00 = (1.f-fx)*(1.f-fy), w10 = fx*(1.f-fy);
            const float w01 = (1.f-fx)*fy,       w11 = fx*fy;
            #pragma unroll
            for (int c = 0; c < 4; ++c) {
                const int dx = c & 1, dy = c >> 1;
                const int xc = x0 + dx, yc = y0 + dy;
                if (xc >= 0 && xc < WL[l] && yc >= 0 && yc < HL[l]) {
                    const float w = (c==0) ? w00 : (c==1) ? w10 : (c==2) ? w01 : w11;
                    const size_t vrow = (size_t)(SL[l] + yc*WL[l] + xc)*BSZ + b;
                    float vv = __bfloat162float(value[vrow*CDIM + h*DH + d]);
                    acc += a * w * vv;
                }
            }
        }
    }
    samp[(size_t)row*CDIM + h*DH + d] = acc;
}

// ---------------- launch ----------------
extern "C" void kernel_launch(void* const* d_in, const int* in_sizes, int n_in,
                              void* d_out, int out_size, void* d_ws, size_t ws_size,
                              hipStream_t stream) {
    (void)in_sizes; (void)n_in; (void)out_size; (void)ws_size;
    const float* tgt    = (const float*)d_in[0];
    const float* qpos   = (const float*)d_in[1];
    const float* refpts = (const float*)d_in[2];
    const float* memory = (const float*)d_in[3];
    const float* Wq  = (const float*)d_in[6];
    const float* Wk  = (const float*)d_in[7];
    const float* Wv  = (const float*)d_in[8];
    const float* Wo  = (const float*)d_in[9];
    const float* Woff= (const float*)d_in[10];
    const float* Watt= (const float*)d_in[11];
    const float* Wval= (const float*)d_in[12];
    const float* Wout= (const float*)d_in[13];
    const float* W1  = (const float*)d_in[14];
    const float* W2  = (const float*)d_in[15];
    const float* bq  = (const float*)d_in[16];
    const float* bk  = (const float*)d_in[17];
    const float* bv  = (const float*)d_in[18];
    const float* bo  = (const float*)d_in[19];
    const float* boff= (const float*)d_in[20];
    const float* batt= (const float*)d_in[21];
    const float* bval= (const float*)d_in[22];
    const float* bout= (const float*)d_in[23];
    const float* b1  = (const float*)d_in[24];
    const float* b2  = (const float*)d_in[25];
    const float* ln1g= (const float*)d_in[26];
    const float* ln1b= (const float*)d_in[27];
    const float* ln2g= (const float*)d_in[28];
    const float* ln2b= (const float*)d_in[29];
    const float* ln3g= (const float*)d_in[30];
    const float* ln3b= (const float*)d_in[31];
    float* out = (float*)d_out;

    char* ws = (char*)d_ws;
    const size_t RB = (size_t)ROWS * CDIM * 4;
    float* tgt2 = (float*)(ws + 0*RB);
    float* tgt3 = (float*)(ws + 1*RB);
    float* qk   = (float*)(ws + 2*RB);
    float* qbuf = (float*)(ws + 3*RB);
    float* kbuf = (float*)(ws + 4*RB);   // also samp
    float* vbuf = (float*)(ws + 5*RB);
    float* abuf = (float*)(ws + 6*RB);
    float* offb = (float*)(ws + 7*RB);                        // 7200x320
    float* awb  = (float*)(ws + 7*RB + (size_t)ROWS*320*4);   // 7200x160
    char*  wsm  = ws + 7*RB + (size_t)ROWS*320*4 + (size_t)ROWS*160*4;
    u16* WqT   = (u16*)(wsm + 0*131072);
    u16* WkT   = (u16*)(wsm + 1*131072);
    u16* WvT   = (u16*)(wsm + 2*131072);
    u16* WoT   = (u16*)(wsm + 3*131072);
    u16* WvalT = (u16*)(wsm + 4*131072);
    u16* WoutT = (u16*)(wsm + 5*131072);
    u16* WoffT = (u16*)(wsm + 6*131072);
    u16* WattT = (u16*)(wsm + 6*131072 + 163840);
    char* big  = wsm + 6*131072 + 163840 + 81920;
    u16* valb  = (u16*)big;                              // 174592x256 bf16 (89 MB)
    u16* W1T   = (u16*)big;                              // reuse after msdeform
    u16* W2T   = (u16*)(big + 1048576);
    u16* ffnh  = (u16*)(big + 2097152);

    const int n4 = ROWS * CDIM / 4;
    const dim3 blk(256);

    // ---- weight transposes ----
    wt_kernel<<<dim3(8,8),  blk, 0, stream>>>(Wq,   WqT,   CDIM, CDIM);
    wt_kernel<<<dim3(8,8),  blk, 0, stream>>>(Wk,   WkT,   CDIM, CDIM);
    wt_kernel<<<dim3(8,8),  blk, 0, stream>>>(Wv,   WvT,   CDIM, CDIM);
    wt_kernel<<<dim3(8,8),  blk, 0, stream>>>(Wo,   WoT,   CDIM, CDIM);
    wt_kernel<<<dim3(8,8),  blk, 0, stream>>>(Wval, WvalT, CDIM, CDIM);
    wt_kernel<<<dim3(8,8),  blk, 0, stream>>>(Wout, WoutT, CDIM, CDIM);
    wt_kernel<<<dim3(10,8), blk, 0, stream>>>(Woff, WoffT, CDIM, 320);
    wt_kernel<<<dim3(5,8),  blk, 0, stream>>>(Watt, WattT, CDIM, 160);

    // ---- stage 1: self-attention ----
    addvec_kernel<<<dim3((n4+255)/256), blk, 0, stream>>>(tgt, qpos, qk, n4);
    gemm_mfma<float,0,float><<<dim3(2,57), blk, 0, stream>>>(qk,  WqT, bq, qbuf, ROWS, CDIM, CDIM);
    gemm_mfma<float,0,float><<<dim3(2,57), blk, 0, stream>>>(qk,  WkT, bk, kbuf, ROWS, CDIM, CDIM);
    gemm_mfma<float,0,float><<<dim3(2,57), blk, 0, stream>>>(tgt, WvT, bv, vbuf, ROWS, CDIM, CDIM);
    attn_mfma_kernel<<<dim3(512), blk, 0, stream>>>(qbuf, kbuf, vbuf, abuf);
    gemm_mfma<float,0,float><<<dim3(2,57), blk, 0, stream>>>(abuf, WoT, bo, qk, ROWS, CDIM, CDIM);
    ln_res_kernel<<<dim3(ROWS/4), blk, 0, stream>>>(qk, tgt, ln2g, ln2b, tgt2);

    // ---- stage 2: deformable cross-attention ----
    gemm_mfma<float,0,u16><<<dim3(2,1364), blk, 0, stream>>>(memory, WvalT, bval, valb, VROWS, CDIM, CDIM);
    addvec_kernel<<<dim3((n4+255)/256), blk, 0, stream>>>(tgt2, qpos, qbuf, n4);
    gemm_mfma<float,0,float><<<dim3(3,57), blk, 0, stream>>>(qbuf, WoffT, boff, offb, ROWS, 320, CDIM);
    gemm_mfma<float,0,float><<<dim3(2,57), blk, 0, stream>>>(qbuf, WattT, batt, awb,  ROWS, 160, CDIM);
    softmax20_kernel<<<dim3((ROWS*NH+255)/256), blk, 0, stream>>>(awb);
    msdeform_kernel<<<dim3(ROWS), blk, 0, stream>>>((const __hip_bfloat16*)valb, offb, awb, refpts, kbuf);
    gemm_mfma<float,0,float><<<dim3(2,57), blk, 0, stream>>>(kbuf, WoutT, bout, vbuf, ROWS, CDIM, CDIM);
    ln_res_kernel<<<dim3(ROWS/4), blk, 0, stream>>>(vbuf, tgt2, ln1g, ln1b, tgt3);

    // ---- stage 3: FFN ----
    wt_kernel<<<dim3(64,8), blk, 0, stream>>>(W1, W1T, CDIM, DFF);
    wt_kernel<<<dim3(8,64), blk, 0, stream>>>(W2, W2T, DFF, CDIM);
    gemm_mfma<float,1,u16><<<dim3(16,57), blk, 0, stream>>>(tgt3, W1T, b1, ffnh, ROWS, DFF, CDIM);
    gemm_mfma<u16,0,float><<<dim3(2,57),  blk, 0, stream>>>(ffnh, W2T, b2, abuf, ROWS, CDIM, DFF);
    ln_res_kernel<<<dim3(ROWS/4), blk, 0, stream>>>(abuf, tgt3, ln3g, ln3b, out);
}

// Round 4
// 552.778 us; speedup vs baseline: 2.1095x; 1.0013x over previous
//
#include <hip/hip_runtime.h>
#include <hip/hip_bf16.h>
#include <type_traits>

#define LQ    900
#define BSZ   8
#define ROWS  (LQ*BSZ)        // 7200
#define CDIM  256
#define NH    8
#define DH    32
#define LVTOT 21824
#define VROWS (LVTOT*BSZ)     // 174592
#define DFF   2048

typedef unsigned short u16;
typedef short short8 __attribute__((ext_vector_type(8)));
typedef float f32x4 __attribute__((ext_vector_type(4)));

__device__ __forceinline__ u16 f2bf(float f) {
    unsigned u = __float_as_uint(f);
    u += 0x7FFF + ((u >> 16) & 1);   // RNE
    return (u16)(u >> 16);
}

// ---------------- elementwise add (float4) ----------------
__global__ __launch_bounds__(256) void addvec_kernel(const float* __restrict__ a,
                                                     const float* __restrict__ b,
                                                     float* __restrict__ c, int n4) {
    int i = blockIdx.x * 256 + threadIdx.x;
    if (i < n4) {
        float4 x = reinterpret_cast<const float4*>(a)[i];
        float4 y = reinterpret_cast<const float4*>(b)[i];
        reinterpret_cast<float4*>(c)[i] = make_float4(x.x+y.x, x.y+y.y, x.z+y.z, x.w+y.w);
    }
}

// ---------------- weight transpose + cvt: W[K][N] f32 -> Wt[N][K] bf16 ----------------
__global__ __launch_bounds__(256) void wt_kernel(const float* __restrict__ W, u16* __restrict__ Wt,
                                                 int K, int N) {
    __shared__ float t[32][33];
    const int n0 = blockIdx.x * 32, k0 = blockIdx.y * 32;
    const int tx = threadIdx.x & 31, ty = threadIdx.x >> 5;
    #pragma unroll
    for (int r = ty; r < 32; r += 8)
        t[r][tx] = W[(size_t)(k0 + r) * N + n0 + tx];
    __syncthreads();
    #pragma unroll
    for (int r = ty; r < 32; r += 8)
        Wt[(size_t)(n0 + r) * K + k0 + tx] = f2bf(t[tx][r]);
}

// ---------------- bf16 MFMA GEMM: C = A @ W + bias ----------------
template<typename AT, int RELU, typename OutT>
__global__ __launch_bounds__(256) void gemm_mfma(const AT* __restrict__ A,
                                                 const u16* __restrict__ Wt,
                                                 const float* __restrict__ bias,
                                                 OutT* __restrict__ C,
                                                 int M, int N, int K) {
    __shared__ __align__(16) u16 As[128 * 64];
    __shared__ __align__(16) u16 Bs[128 * 64];
    const int tid = threadIdx.x;
    const int m0 = blockIdx.y * 128, n0 = blockIdx.x * 128;
    const int lane = tid & 63;
    const int wr = (tid >> 7) & 1, wc = (tid >> 6) & 1;
    const int lr = lane & 15, lg = lane >> 4;
    const int sr = tid >> 1;
    const int sc = (tid & 1) * 4;

    f32x4 acc[4][4] = {};

    for (int k0 = 0; k0 < K; k0 += 64) {
        {
            u16 tmp[32];
            const int grow = m0 + sr;
            if (grow < M) {
                if constexpr (std::is_same<AT, float>::value) {
                    const float4* src = reinterpret_cast<const float4*>(&A[(size_t)grow * K + k0 + sc * 8]);
                    #pragma unroll
                    for (int i = 0; i < 8; ++i) {
                        float4 v = src[i];
                        tmp[i*4+0] = f2bf(v.x); tmp[i*4+1] = f2bf(v.y);
                        tmp[i*4+2] = f2bf(v.z); tmp[i*4+3] = f2bf(v.w);
                    }
                } else {
                    const uint4* src = reinterpret_cast<const uint4*>(&A[(size_t)grow * K + k0 + sc * 8]);
                    #pragma unroll
                    for (int i = 0; i < 4; ++i)
                        *reinterpret_cast<uint4*>(&tmp[i*8]) = src[i];
                }
            } else {
                #pragma unroll
                for (int i = 0; i < 32; ++i) tmp[i] = 0;
            }
            #pragma unroll
            for (int c4 = 0; c4 < 4; ++c4) {
                const int c = sc + c4;
                *reinterpret_cast<uint4*>(&As[sr*64 + ((c ^ (sr & 7)) * 8)]) =
                    *reinterpret_cast<const uint4*>(&tmp[c4*8]);
            }
        }
        {
            u16 tmp[32];
            const int gcol = n0 + sr;
            if (gcol < N) {
                const uint4* src = reinterpret_cast<const uint4*>(&Wt[(size_t)gcol * K + k0 + sc * 8]);
                #pragma unroll
                for (int i = 0; i < 4; ++i)
                    *reinterpret_cast<uint4*>(&tmp[i*8]) = src[i];
            } else {
                #pragma unroll
                for (int i = 0; i < 32; ++i) tmp[i] = 0;
            }
            #pragma unroll
            for (int c4 = 0; c4 < 4; ++c4) {
                const int c = sc + c4;
                *reinterpret_cast<uint4*>(&Bs[sr*64 + ((c ^ (sr & 7)) * 8)]) =
                    *reinterpret_cast<const uint4*>(&tmp[c4*8]);
            }
        }
        __syncthreads();
        #pragma unroll
        for (int h = 0; h < 2; ++h) {
            short8 af[4], bfr[4];
            #pragma unroll
            for (int i = 0; i < 4; ++i) {
                const int r = wr*64 + i*16 + lr;
                af[i] = *reinterpret_cast<const short8*>(&As[r*64 + (((h*4 + lg) ^ (r & 7)) * 8)]);
            }
            #pragma unroll
            for (int j = 0; j < 4; ++j) {
                const int r = wc*64 + j*16 + lr;
                bfr[j] = *reinterpret_cast<const short8*>(&Bs[r*64 + (((h*4 + lg) ^ (r & 7)) * 8)]);
            }
            #pragma unroll
            for (int i = 0; i < 4; ++i)
                #pragma unroll
                for (int j = 0; j < 4; ++j)
                    acc[i][j] = __builtin_amdgcn_mfma_f32_16x16x32_bf16(af[i], bfr[j], acc[i][j], 0, 0, 0);
        }
        __syncthreads();
    }
    #pragma unroll
    for (int j = 0; j < 4; ++j) {
        const int col = n0 + wc*64 + j*16 + lr;
        if (col >= N) continue;
        const float bcol = bias[col];
        #pragma unroll
        for (int i = 0; i < 4; ++i) {
            #pragma unroll
            for (int r = 0; r < 4; ++r) {
                const int row = m0 + wr*64 + i*16 + lg*4 + r;
                if (row >= M) continue;
                float v = acc[i][j][r] + bcol;
                if (RELU) v = fmaxf(v, 0.f);
                if constexpr (std::is_same<OutT, float>::value)
                    C[(size_t)row * N + col] = v;
                else
                    C[(size_t)row * N + col] = f2bf(v);
            }
        }
    }
}

// ---------------- MFMA flash self-attention ----------------
// q,k,v f32 (lq*B+b, h*32+d). Block = (b,h,qt): 128 queries, 4 waves x 32 q.
// S^T = mfma(K,Q) so each lane's column is a query and P is lane-local for PV.
__global__ __launch_bounds__(256) void attn_mfma_kernel(const float* __restrict__ q,
                                                        const float* __restrict__ k,
                                                        const float* __restrict__ v,
                                                        float* __restrict__ out) {
    __shared__ __align__(16) u16 Ks[64*32];   // [key][32 d], 16B chunk c stored at c^((key>>1)&3)
    __shared__ __align__(16) u16 Vt[32*64];   // [dh][64 key], 16B chunk c stored at c^(dh&7)
    const int bx = blockIdx.x;
    const int qt = bx & 7, h = (bx >> 3) & 7, b = bx >> 6;
    const int tid = threadIdx.x;
    const int w = tid >> 6, lane = tid & 63;
    const int lr = lane & 15, lg = lane >> 4;
    const int m0 = qt*128 + w*32;
    const float scale = 0.1767766952966369f;

    // Q B-fragments (col = query = lr + j*16, k-elem = lg*8+e), scale folded in
    short8 qf[2];
    #pragma unroll
    for (int j = 0; j < 2; ++j) {
        int lq = m0 + j*16 + lr; if (lq > LQ-1) lq = LQ-1;
        const float* qp = &q[((size_t)lq*BSZ + b)*CDIM + h*DH + lg*8];
        float4 a = *reinterpret_cast<const float4*>(qp);
        float4 c = *reinterpret_cast<const float4*>(qp + 4);
        u16 t[8] = { f2bf(a.x*scale), f2bf(a.y*scale), f2bf(a.z*scale), f2bf(a.w*scale),
                     f2bf(c.x*scale), f2bf(c.y*scale), f2bf(c.z*scale), f2bf(c.w*scale) };
        qf[j] = *reinterpret_cast<short8*>(t);
    }

    f32x4 o00 = {}, o01 = {}, o10 = {}, o11 = {};   // o[dh-frag][q-frag]
    float m[2] = {-1e30f, -1e30f}, l[2] = {0.f, 0.f};
    const f32x4 zero = {};

    for (int kt = 0; kt < 15; ++kt) {
        __syncthreads();
        // ---- stage K (row-major swz) and V (transposed swz) ----
        {
            const int key = tid >> 2, c = tid & 3;
            int kg = kt*64 + key; if (kg > LQ-1) kg = LQ-1;
            const size_t base = ((size_t)kg*BSZ + b)*CDIM + h*DH + c*8;
            float4 k0 = *reinterpret_cast<const float4*>(&k[base]);
            float4 k1 = *reinterpret_cast<const float4*>(&k[base+4]);
            float4 v0 = *reinterpret_cast<const float4*>(&v[base]);
            float4 v1 = *reinterpret_cast<const float4*>(&v[base+4]);
            u16 kb[8] = { f2bf(k0.x), f2bf(k0.y), f2bf(k0.z), f2bf(k0.w),
                          f2bf(k1.x), f2bf(k1.y), f2bf(k1.z), f2bf(k1.w) };
            *reinterpret_cast<short8*>(&Ks[key*32 + ((c ^ ((key>>1)&3)) * 8)]) =
                *reinterpret_cast<short8*>(kb);
            float vv[8] = { v0.x, v0.y, v0.z, v0.w, v1.x, v1.y, v1.z, v1.w };
            #pragma unroll
            for (int e = 0; e < 8; ++e) {
                const int dh = c*8 + e;
                Vt[dh*64 + (((key>>3) ^ (dh&7)) * 8) + (key&7)] = f2bf(vv[e]);
            }
        }
        __syncthreads();

        // ---- S^T = K @ Q^T : rows=keys (4 frags), cols=queries (2 frags) ----
        f32x4 s[4][2];
        #pragma unroll
        for (int i = 0; i < 4; ++i) {
            const int key = i*16 + lr;
            short8 kf = *reinterpret_cast<const short8*>(&Ks[key*32 + ((lg ^ ((key>>1)&3)) * 8)]);
            s[i][0] = __builtin_amdgcn_mfma_f32_16x16x32_bf16(kf, qf[0], zero, 0, 0, 0);
            s[i][1] = __builtin_amdgcn_mfma_f32_16x16x32_bf16(kf, qf[1], zero, 0, 0, 0);
        }
        // ---- mask invalid keys (key = kt*64 + i*16 + lg*4 + r) ----
        const int lim = LQ - kt*64 - lg*4;
        #pragma unroll
        for (int i = 0; i < 4; ++i)
            #pragma unroll
            for (int r = 0; r < 4; ++r)
                if (i*16 + r >= lim) { s[i][0][r] = -1e30f; s[i][1][r] = -1e30f; }

        // ---- online softmax per query column (j selects 16 queries) ----
        #pragma unroll
        for (int j = 0; j < 2; ++j) {
            float mx = -1e30f;
            #pragma unroll
            for (int i = 0; i < 4; ++i)
                #pragma unroll
                for (int r = 0; r < 4; ++r) mx = fmaxf(mx, s[i][j][r]);
            mx = fmaxf(mx, __shfl_xor(mx, 16));
            mx = fmaxf(mx, __shfl_xor(mx, 32));
            const float mn = fmaxf(m[j], mx);
            const float corr = __expf(m[j] - mn);
            float sum = 0.f;
            #pragma unroll
            for (int i = 0; i < 4; ++i)
                #pragma unroll
                for (int r = 0; r < 4; ++r) {
                    float p = __expf(s[i][j][r] - mn);
                    s[i][j][r] = p;
                    sum += p;
                }
            sum += __shfl_xor(sum, 16);
            sum += __shfl_xor(sum, 32);
            l[j] = l[j]*corr + sum;
            m[j] = mn;
            if (j == 0) { o00 *= corr; o10 *= corr; }
            else        { o01 *= corr; o11 *= corr; }
        }

        // ---- pack P^T B-frags: elem e<4 -> key kh*32+lg*4+e, e>=4 -> +16 ----
        short8 pb[2][2];
        #pragma unroll
        for (int kh = 0; kh < 2; ++kh)
            #pragma unroll
            for (int j = 0; j < 2; ++j) {
                u16 t[8];
                #pragma unroll
                for (int e = 0; e < 4; ++e) {
                    t[e]   = f2bf(s[2*kh][j][e]);
                    t[e+4] = f2bf(s[2*kh+1][j][e]);
                }
                pb[kh][j] = *reinterpret_cast<short8*>(t);
            }

        // ---- PV: O^T[dh][q] += V^T-frag x P^T-frag (same k-bijection) ----
        #pragma unroll
        for (int ip = 0; ip < 2; ++ip) {
            const int dh = ip*16 + lr;
            #pragma unroll
            for (int kh = 0; kh < 2; ++kh) {
                u16 t[8];
                const int c0 = (kh*4 + (lg>>1)) ^ (dh&7);
                const int c1 = (kh*4 + 2 + (lg>>1)) ^ (dh&7);
                *reinterpret_cast<uint2*>(&t[0]) =
                    *reinterpret_cast<const uint2*>(&Vt[dh*64 + c0*8 + (lg&1)*4]);
                *reinterpret_cast<uint2*>(&t[4]) =
                    *reinterpret_cast<const uint2*>(&Vt[dh*64 + c1*8 + (lg&1)*4]);
                short8 vf = *reinterpret_cast<short8*>(t);
                if (ip == 0) {
                    o00 = __builtin_amdgcn_mfma_f32_16x16x32_bf16(vf, pb[kh][0], o00, 0, 0, 0);
                    o01 = __builtin_amdgcn_mfma_f32_16x16x32_bf16(vf, pb[kh][1], o01, 0, 0, 0);
                } else {
                    o10 = __builtin_amdgcn_mfma_f32_16x16x32_bf16(vf, pb[kh][0], o10, 0, 0, 0);
                    o11 = __builtin_amdgcn_mfma_f32_16x16x32_bf16(vf, pb[kh][1], o11, 0, 0, 0);
                }
            }
        }
    }

    // ---- store O (O^T frag: col=query=lr+j*16, row=dh=ip*16+lg*4+r) ----
    #pragma unroll
    for (int j = 0; j < 2; ++j) {
        const int lq = m0 + j*16 + lr;
        if (lq >= LQ) continue;
        const float inv = 1.f / l[j];
        float* op = &out[((size_t)lq*BSZ + b)*CDIM + h*DH];
        #pragma unroll
        for (int r = 0; r < 4; ++r) {
            const f32x4& a0 = (j == 0) ? o00 : o01;
            const f32x4& a1 = (j == 0) ? o10 : o11;
            op[lg*4 + r]      = a0[r] * inv;
            op[16 + lg*4 + r] = a1[r] * inv;
        }
    }
}

// ---------------- fused residual + LayerNorm ----------------
__global__ __launch_bounds__(256) void ln_res_kernel(const float* __restrict__ xin,
                                                     const float* __restrict__ res,
                                                     const float* __restrict__ g,
                                                     const float* __restrict__ beta,
                                                     float* __restrict__ out) {
    const int row  = blockIdx.x * 4 + (threadIdx.x >> 6);
    const int lane = threadIdx.x & 63;
    const size_t base = (size_t)row * CDIM + lane * 4;
    float4 a = *reinterpret_cast<const float4*>(&xin[base]);
    float4 r = *reinterpret_cast<const float4*>(&res[base]);
    float x0 = a.x+r.x, x1 = a.y+r.y, x2 = a.z+r.z, x3 = a.w+r.w;
    float s = x0+x1+x2+x3;
    #pragma unroll
    for (int o = 1; o < 64; o <<= 1) s += __shfl_xor(s, o);
    float mean = s * (1.f/256.f);
    float d0 = x0-mean, d1 = x1-mean, d2 = x2-mean, d3 = x3-mean;
    float sq = d0*d0 + d1*d1 + d2*d2 + d3*d3;
    #pragma unroll
    for (int o = 1; o < 64; o <<= 1) sq += __shfl_xor(sq, o);
    float rs = rsqrtf(sq * (1.f/256.f) + 1e-5f);
    float4 gg = *reinterpret_cast<const float4*>(&g[lane*4]);
    float4 bb = *reinterpret_cast<const float4*>(&beta[lane*4]);
    float4 o4 = make_float4(d0*rs*gg.x+bb.x, d1*rs*gg.y+bb.y, d2*rs*gg.z+bb.z, d3*rs*gg.w+bb.w);
    *reinterpret_cast<float4*>(&out[base]) = o4;
}

// ---------------- softmax over 20 ----------------
__global__ __launch_bounds__(256) void softmax20_kernel(float* __restrict__ aw) {
    int item = blockIdx.x * 256 + threadIdx.x;
    if (item >= ROWS * NH) return;
    int row = item >> 3, h = item & 7;
    float* p = &aw[(size_t)row*160 + h*20];
    float mx = -1e30f;
    float e[20];
    #pragma unroll
    for (int j = 0; j < 20; ++j) mx = fmaxf(mx, p[j]);
    float sum = 0.f;
    #pragma unroll
    for (int j = 0; j < 20; ++j) { e[j] = __expf(p[j] - mx); sum += e[j]; }
    float inv = 1.f / sum;
    #pragma unroll
    for (int j = 0; j < 20; ++j) p[j] = e[j] * inv;
}

// ---------------- ms-deformable sampling ----------------
__global__ __launch_bounds__(256) void msdeform_kernel(const __hip_bfloat16* __restrict__ value,
                                                       const float* __restrict__ off,
                                                       const float* __restrict__ aw,
                                                       const float* __restrict__ refp,
                                                       float* __restrict__ samp) {
    const int gid = blockIdx.x * 8 + (threadIdx.x >> 5);
    const int d   = threadIdx.x & 31;
    const int h   = gid & 7;
    const int row = gid >> 3;
    const int b   = row & 7;
    const int HL[5] = {128, 64, 32, 16, 8};
    const int WL[5] = {128, 64, 32, 16, 8};
    const int SL[5] = {0, 16384, 20480, 21504, 21760};
    float acc = 0.f;
    #pragma unroll
    for (int l = 0; l < 5; ++l) {
        const float rx = refp[((size_t)row*5 + l)*2 + 0];
        const float ry = refp[((size_t)row*5 + l)*2 + 1];
        const float Wf = (float)WL[l], Hf = (float)HL[l];
        #pragma unroll
        for (int p = 0; p < 4; ++p) {
            const int oc = ((h*5 + l)*4 + p)*2;
            const float ox = off[(size_t)row*320 + oc];
            const float oy = off[(size_t)row*320 + oc + 1];
            const float a  = aw[(size_t)row*160 + h*20 + l*4 + p];
            const float x = (rx + ox / Wf) * Wf - 0.5f;
            const float y = (ry + oy / Hf) * Hf - 0.5f;
            const float x0f = floorf(x), y0f = floorf(y);
            const float fx = x - x0f, fy = y - y0f;
            const int x0 = (int)x0f, y0 = (int)y0f;
            const float w00 = (1.f-fx)*(1.f-fy), w10 = fx*(1.f-fy);
            const float w01 = (1.f-fx)*fy,       w11 = fx*fy;
            #pragma unroll
            for (int c = 0; c < 4; ++c) {
                const int dx = c & 1, dy = c >> 1;
                const int xc = x0 + dx, yc = y0 + dy;
                if (xc >= 0 && xc < WL[l] && yc >= 0 && yc < HL[l]) {
                    const float w = (c==0) ? w00 : (c==1) ? w10 : (c==2) ? w01 : w11;
                    const size_t vrow = (size_t)(SL[l] + yc*WL[l] + xc)*BSZ + b;
                    float vv = __bfloat162float(value[vrow*CDIM + h*DH + d]);
                    acc += a * w * vv;
                }
            }
        }
    }
    samp[(size_t)row*CDIM + h*DH + d] = acc;
}

// ---------------- launch ----------------
extern "C" void kernel_launch(void* const* d_in, const int* in_sizes, int n_in,
                              void* d_out, int out_size, void* d_ws, size_t ws_size,
                              hipStream_t stream) {
    (void)in_sizes; (void)n_in; (void)out_size; (void)ws_size;
    const float* tgt    = (const float*)d_in[0];
    const float* qpos   = (const float*)d_in[1];
    const float* refpts = (const float*)d_in[2];
    const float* memory = (const float*)d_in[3];
    const float* Wq  = (const float*)d_in[6];
    const float* Wk  = (const float*)d_in[7];
    const float* Wv  = (const float*)d_in[8];
    const float* Wo  = (const float*)d_in[9];
    const float* Woff= (const float*)d_in[10];
    const float* Watt= (const float*)d_in[11];
    const float* Wval= (const float*)d_in[12];
    const float* Wout= (const float*)d_in[13];
    const float* W1  = (const float*)d_in[14];
    const float* W2  = (const float*)d_in[15];
    const float* bq  = (const float*)d_in[16];
    const float* bk  = (const float*)d_in[17];
    const float* bv  = (const float*)d_in[18];
    const float* bo  = (const float*)d_in[19];
    const float* boff= (const float*)d_in[20];
    const float* batt= (const float*)d_in[21];
    const float* bval= (const float*)d_in[22];
    const float* bout= (const float*)d_in[23];
    const float* b1  = (const float*)d_in[24];
    const float* b2  = (const float*)d_in[25];
    const float* ln1g= (const float*)d_in[26];
    const float* ln1b= (const float*)d_in[27];
    const float* ln2g= (const float*)d_in[28];
    const float* ln2b= (const float*)d_in[29];
    const float* ln3g= (const float*)d_in[30];
    const float* ln3b= (const float*)d_in[31];
    float* out = (float*)d_out;

    char* ws = (char*)d_ws;
    const size_t RB = (size_t)ROWS * CDIM * 4;
    float* tgt2 = (float*)(ws + 0*RB);
    float* tgt3 = (float*)(ws + 1*RB);
    float* qk   = (float*)(ws + 2*RB);
    float* qbuf = (float*)(ws + 3*RB);
    float* kbuf = (float*)(ws + 4*RB);   // also samp
    float* vbuf = (float*)(ws + 5*RB);
    float* abuf = (float*)(ws + 6*RB);
    float* offb = (float*)(ws + 7*RB);                        // 7200x320
    float* awb  = (float*)(ws + 7*RB + (size_t)ROWS*320*4);   // 7200x160
    char*  wsm  = ws + 7*RB + (size_t)ROWS*320*4 + (size_t)ROWS*160*4;
    u16* WqT   = (u16*)(wsm + 0*131072);
    u16* WkT   = (u16*)(wsm + 1*131072);
    u16* WvT   = (u16*)(wsm + 2*131072);
    u16* WoT   = (u16*)(wsm + 3*131072);
    u16* WvalT = (u16*)(wsm + 4*131072);
    u16* WoutT = (u16*)(wsm + 5*131072);
    u16* WoffT = (u16*)(wsm + 6*131072);
    u16* WattT = (u16*)(wsm + 6*131072 + 163840);
    char* big  = wsm + 6*131072 + 163840 + 81920;
    u16* valb  = (u16*)big;                              // 174592x256 bf16 (89 MB)
    u16* W1T   = (u16*)big;                              // reuse after msdeform
    u16* W2T   = (u16*)(big + 1048576);
    u16* ffnh  = (u16*)(big + 2097152);

    const int n4 = ROWS * CDIM / 4;
    const dim3 blk(256);

    // ---- weight transposes ----
    wt_kernel<<<dim3(8,8),  blk, 0, stream>>>(Wq,   WqT,   CDIM, CDIM);
    wt_kernel<<<dim3(8,8),  blk, 0, stream>>>(Wk,   WkT,   CDIM, CDIM);
    wt_kernel<<<dim3(8,8),  blk, 0, stream>>>(Wv,   WvT,   CDIM, CDIM);
    wt_kernel<<<dim3(8,8),  blk, 0, stream>>>(Wo,   WoT,   CDIM, CDIM);
    wt_kernel<<<dim3(8,8),  blk, 0, stream>>>(Wval, WvalT, CDIM, CDIM);
    wt_kernel<<<dim3(8,8),  blk, 0, stream>>>(Wout, WoutT, CDIM, CDIM);
    wt_kernel<<<dim3(10,8), blk, 0, stream>>>(Woff, WoffT, CDIM, 320);
    wt_kernel<<<dim3(5,8),  blk, 0, stream>>>(Watt, WattT, CDIM, 160);

    // ---- stage 1: self-attention ----
    addvec_kernel<<<dim3((n4+255)/256), blk, 0, stream>>>(tgt, qpos, qk, n4);
    gemm_mfma<float,0,float><<<dim3(2,57), blk, 0, stream>>>(qk,  WqT, bq, qbuf, ROWS, CDIM, CDIM);
    gemm_mfma<float,0,float><<<dim3(2,57), blk, 0, stream>>>(qk,  WkT, bk, kbuf, ROWS, CDIM, CDIM);
    gemm_mfma<float,0,float><<<dim3(2,57), blk, 0, stream>>>(tgt, WvT, bv, vbuf, ROWS, CDIM, CDIM);
    attn_mfma_kernel<<<dim3(512), blk, 0, stream>>>(qbuf, kbuf, vbuf, abuf);
    gemm_mfma<float,0,float><<<dim3(2,57), blk, 0, stream>>>(abuf, WoT, bo, qk, ROWS, CDIM, CDIM);
    ln_res_kernel<<<dim3(ROWS/4), blk, 0, stream>>>(qk, tgt, ln2g, ln2b, tgt2);

    // ---- stage 2: deformable cross-attention ----
    gemm_mfma<float,0,u16><<<dim3(2,1364), blk, 0, stream>>>(memory, WvalT, bval, valb, VROWS, CDIM, CDIM);
    addvec_kernel<<<dim3((n4+255)/256), blk, 0, stream>>>(tgt2, qpos, qbuf, n4);
    gemm_mfma<float,0,float><<<dim3(3,57), blk, 0, stream>>>(qbuf, WoffT, boff, offb, ROWS, 320, CDIM);
    gemm_mfma<float,0,float><<<dim3(2,57), blk, 0, stream>>>(qbuf, WattT, batt, awb,  ROWS, 160, CDIM);
    softmax20_kernel<<<dim3((ROWS*NH+255)/256), blk, 0, stream>>>(awb);
    msdeform_kernel<<<dim3(ROWS), blk, 0, stream>>>((const __hip_bfloat16*)valb, offb, awb, refpts, kbuf);
    gemm_mfma<float,0,float><<<dim3(2,57), blk, 0, stream>>>(kbuf, WoutT, bout, vbuf, ROWS, CDIM, CDIM);
    ln_res_kernel<<<dim3(ROWS/4), blk, 0, stream>>>(vbuf, tgt2, ln1g, ln1b, tgt3);

    // ---- stage 3: FFN ----
    wt_kernel<<<dim3(64,8), blk, 0, stream>>>(W1, W1T, CDIM, DFF);
    wt_kernel<<<dim3(8,64), blk, 0, stream>>>(W2, W2T, DFF, CDIM);
    gemm_mfma<float,1,u16><<<dim3(16,57), blk, 0, stream>>>(tgt3, W1T, b1, ffnh, ROWS, DFF, CDIM);
    gemm_mfma<u16,0,float><<<dim3(2,57),  blk, 0, stream>>>(ffnh, W2T, b2, abuf, ROWS, CDIM, DFF);
    ln_res_kernel<<<dim3(ROWS/4), blk, 0, stream>>>(abuf, tgt3, ln3g, ln3b, out);
}

// Round 5
// 446.120 us; speedup vs baseline: 2.6139x; 1.2391x over previous
//
#include <hip/hip_runtime.h>
#include <hip/hip_bf16.h>
#include <type_traits>

#define LQ    900
#define BSZ   8
#define ROWS  (LQ*BSZ)        // 7200
#define CDIM  256
#define QKS   512             // merged q|k row stride
#define OAS   480             // merged off|aw row stride
#define NH    8
#define DH    32
#define LVTOT 21824
#define VROWS (LVTOT*BSZ)     // 174592
#define DFF   2048

typedef unsigned short u16;
typedef short short8 __attribute__((ext_vector_type(8)));
typedef float f32x4 __attribute__((ext_vector_type(4)));

__device__ __forceinline__ u16 f2bf(float f) {
    __hip_bfloat16 h = __float2bfloat16(f);
    return *reinterpret_cast<u16*>(&h);
}

// ---------------- elementwise add (float4) ----------------
__global__ __launch_bounds__(256) void addvec_kernel(const float* __restrict__ a,
                                                     const float* __restrict__ b,
                                                     float* __restrict__ c, int n4) {
    int i = blockIdx.x * 256 + threadIdx.x;
    if (i < n4) {
        float4 x = reinterpret_cast<const float4*>(a)[i];
        float4 y = reinterpret_cast<const float4*>(b)[i];
        reinterpret_cast<float4*>(c)[i] = make_float4(x.x+y.x, x.y+y.y, x.z+y.z, x.w+y.w);
    }
}

// ---------------- weight transpose + cvt: W[K][N] f32 -> Wt[N][K] bf16 ----------------
__global__ __launch_bounds__(256) void wt_kernel(const float* __restrict__ W, u16* __restrict__ Wt,
                                                 int K, int N) {
    __shared__ float t[32][33];
    const int n0 = blockIdx.x * 32, k0 = blockIdx.y * 32;
    const int tx = threadIdx.x & 31, ty = threadIdx.x >> 5;
    #pragma unroll
    for (int r = ty; r < 32; r += 8)
        t[r][tx] = W[(size_t)(k0 + r) * N + n0 + tx];
    __syncthreads();
    #pragma unroll
    for (int r = ty; r < 32; r += 8)
        Wt[(size_t)(n0 + r) * K + k0 + tx] = f2bf(t[tx][r]);
}

// six 256x256 transposes in one dispatch
struct Wt6 { const float* s0; const float* s1; const float* s2; const float* s3; const float* s4; const float* s5;
             u16* d0; u16* d1; u16* d2; u16* d3; u16* d4; u16* d5; };
__global__ __launch_bounds__(256) void wt6_kernel(Wt6 a) {
    __shared__ float t[32][33];
    const float* W; u16* Wt;
    switch (blockIdx.z) {
        case 0: W = a.s0; Wt = a.d0; break;
        case 1: W = a.s1; Wt = a.d1; break;
        case 2: W = a.s2; Wt = a.d2; break;
        case 3: W = a.s3; Wt = a.d3; break;
        case 4: W = a.s4; Wt = a.d4; break;
        default: W = a.s5; Wt = a.d5; break;
    }
    const int n0 = blockIdx.x * 32, k0 = blockIdx.y * 32;
    const int tx = threadIdx.x & 31, ty = threadIdx.x >> 5;
    #pragma unroll
    for (int r = ty; r < 32; r += 8)
        t[r][tx] = W[(size_t)(k0 + r) * 256 + n0 + tx];
    __syncthreads();
    #pragma unroll
    for (int r = ty; r < 32; r += 8)
        Wt[(size_t)(n0 + r) * 256 + k0 + tx] = f2bf(t[tx][r]);
}

// bias concat: bqk = [bq|bk] (512), boa = [boff|batt] (480)
__global__ __launch_bounds__(256) void biascat_kernel(const float* bq, const float* bk, float* bqk,
                                                      const float* boff, const float* batt, float* boa) {
    int t = blockIdx.x * 256 + threadIdx.x;
    if (t < 256) bqk[t] = bq[t];
    else if (t < 512) bqk[t] = bk[t - 256];
    else if (t < 832) boa[t - 512] = boff[t - 512];
    else if (t < 992) boa[t - 832 + 320] = batt[t - 832];
}

// ---------------- staging helpers ----------------
// B tile: LDS linear dest, inverse-swizzled global source (chunk c of row r holds global chunk c^(r&7))
__device__ __forceinline__ void stage_B(const u16* __restrict__ Wt, u16* bsb,
                                        int n0, int k0, int K, int tid) {
    #pragma unroll
    for (int i = 0; i < 4; ++i) {
        const int gi = i*256 + tid;
        const int row = gi >> 3, c = gi & 7;
        const u16* gsrc = Wt + (size_t)(n0 + row) * K + k0 + ((c ^ (row & 7)) << 3);
        u16* ldst = bsb + ((i*256 + (tid & 192)) << 3);
        __builtin_amdgcn_global_load_lds((const __attribute__((address_space(1))) void*)gsrc,
                                         (__attribute__((address_space(3))) void*)ldst, 16, 0, 0);
    }
}

__device__ __forceinline__ void stage_A_bf16(const u16* __restrict__ A, u16* bsa,
                                             int M, int K, int m0, int k0, int tid) {
    #pragma unroll
    for (int i = 0; i < 4; ++i) {
        const int gi = i*256 + tid;
        const int row = gi >> 3, c = gi & 7;
        int grow = m0 + row; if (grow >= M) grow = M - 1;   // clamp; junk rows masked at store
        const u16* gsrc = A + (size_t)grow * K + k0 + ((c ^ (row & 7)) << 3);
        u16* ldst = bsa + ((i*256 + (tid & 192)) << 3);
        __builtin_amdgcn_global_load_lds((const __attribute__((address_space(1))) void*)gsrc,
                                         (__attribute__((address_space(3))) void*)ldst, 16, 0, 0);
    }
}

__device__ __forceinline__ void load_A_f32(float* areg, const float* __restrict__ A,
                                           int M, int K, int m0, int k0, int tid) {
    const int sr = tid >> 1, sc = (tid & 1) * 4;
    const int grow = m0 + sr;
    if (grow < M) {
        const float4* src = reinterpret_cast<const float4*>(&A[(size_t)grow * K + k0 + sc * 8]);
        #pragma unroll
        for (int i = 0; i < 8; ++i)
            *reinterpret_cast<float4*>(&areg[i*4]) = src[i];
    } else {
        #pragma unroll
        for (int i = 0; i < 32; ++i) areg[i] = 0.f;
    }
}

__device__ __forceinline__ void write_A(u16* bsa, const float* areg, int tid) {
    const int sr = tid >> 1, sc = (tid & 1) * 4;
    u16 tmp[32];
    #pragma unroll
    for (int i = 0; i < 32; ++i) tmp[i] = f2bf(areg[i]);
    #pragma unroll
    for (int c4 = 0; c4 < 4; ++c4) {
        const int c = sc + c4;
        *reinterpret_cast<uint4*>(&bsa[sr*64 + ((c ^ (sr & 7)) * 8)]) =
            *reinterpret_cast<const uint4*>(&tmp[c4*8]);
    }
}

// ---------------- bf16 MFMA GEMM: C = A @ Wt^T + bias ----------------
// 128x128 tile, BK=64, double-buffered LDS, one barrier per K-step.
template<typename AT, int RELU, typename OutT>
__global__ __launch_bounds__(256) void gemm_mfma(const AT* __restrict__ A,
                                                 const u16* __restrict__ Wt,
                                                 const float* __restrict__ bias,
                                                 OutT* __restrict__ C,
                                                 int M, int N, int K) {
    __shared__ __align__(16) u16 As[2][128*64];
    __shared__ __align__(16) u16 Bs[2][128*64];
    const int tid = threadIdx.x;
    const int m0 = blockIdx.y * 128, n0 = blockIdx.x * 128;
    const int lane = tid & 63;
    const int wr = (tid >> 7) & 1, wc = (tid >> 6) & 1;
    const int lr = lane & 15, lg = lane >> 4;
    const int nsteps = K >> 6;

    f32x4 acc[4][4] = {};
    float areg[32];

    // prologue: stage tile 0
    stage_B(Wt, Bs[0], n0, 0, K, tid);
    if constexpr (std::is_same<AT, float>::value) {
        load_A_f32(areg, A, M, K, m0, 0, tid);
        write_A(As[0], areg, tid);
    } else {
        stage_A_bf16((const u16*)A, As[0], M, K, m0, 0, tid);
    }
    __syncthreads();

    for (int t = 0; t < nsteps; ++t) {
        const int cur = t & 1;
        if (t + 1 < nsteps) {
            stage_B(Wt, Bs[cur ^ 1], n0, (t+1) << 6, K, tid);
            if constexpr (std::is_same<AT, float>::value)
                load_A_f32(areg, A, M, K, m0, (t+1) << 6, tid);
            else
                stage_A_bf16((const u16*)A, As[cur ^ 1], M, K, m0, (t+1) << 6, tid);
        }
        #pragma unroll
        for (int h = 0; h < 2; ++h) {
            short8 af[4], bfr[4];
            #pragma unroll
            for (int i = 0; i < 4; ++i) {
                const int r = wr*64 + i*16 + lr;
                af[i] = *reinterpret_cast<const short8*>(&As[cur][r*64 + (((h*4 + lg) ^ (r & 7)) * 8)]);
            }
            #pragma unroll
            for (int j = 0; j < 4; ++j) {
                const int r = wc*64 + j*16 + lr;
                bfr[j] = *reinterpret_cast<const short8*>(&Bs[cur][r*64 + (((h*4 + lg) ^ (r & 7)) * 8)]);
            }
            #pragma unroll
            for (int i = 0; i < 4; ++i)
                #pragma unroll
                for (int j = 0; j < 4; ++j)
                    acc[i][j] = __builtin_amdgcn_mfma_f32_16x16x32_bf16(af[i], bfr[j], acc[i][j], 0, 0, 0);
        }
        if (t + 1 < nsteps) {
            if constexpr (std::is_same<AT, float>::value)
                write_A(As[cur ^ 1], areg, tid);
        }
        __syncthreads();
    }

    if constexpr (std::is_same<OutT, float>::value) {
        // direct guarded stores (small outputs)
        #pragma unroll
        for (int j = 0; j < 4; ++j) {
            const int col = n0 + wc*64 + j*16 + lr;
            if (col >= N) continue;
            const float bcol = bias[col];
            #pragma unroll
            for (int i = 0; i < 4; ++i) {
                #pragma unroll
                for (int r = 0; r < 4; ++r) {
                    const int row = m0 + wr*64 + i*16 + lg*4 + r;
                    if (row >= M) continue;
                    float v = acc[i][j][r] + bcol;
                    if (RELU) v = fmaxf(v, 0.f);
                    C[(size_t)row * N + col] = v;
                }
            }
        }
    } else {
        // LDS-staged coalesced bf16 epilogue (N multiple of 128 on this path)
        u16* Ct = &As[0][0];   // 32 KB = 128x128 bf16
        #pragma unroll
        for (int j = 0; j < 4; ++j) {
            const int col = wc*64 + j*16 + lr;
            const float bcol = bias[n0 + col];
            #pragma unroll
            for (int i = 0; i < 4; ++i)
                #pragma unroll
                for (int r = 0; r < 4; ++r) {
                    float v = acc[i][j][r] + bcol;
                    if (RELU) v = fmaxf(v, 0.f);
                    Ct[(wr*64 + i*16 + lg*4 + r)*128 + col] = f2bf(v);
                }
        }
        __syncthreads();
        #pragma unroll
        for (int it = 0; it < 8; ++it) {
            const int idx = it*256 + tid;
            const int row = idx >> 4, cc = idx & 15;
            if (m0 + row < M)
                *reinterpret_cast<uint4*>(&C[(size_t)(m0 + row) * N + n0 + cc*8]) =
                    *reinterpret_cast<const uint4*>(&Ct[row*128 + cc*8]);
        }
    }
}

// ---------------- MFMA flash self-attention ----------------
// qk merged buffer (row stride 512: q at 0, k at 256), v separate (stride 256).
__global__ __launch_bounds__(256) void attn_mfma_kernel(const float* __restrict__ qk,
                                                        const float* __restrict__ v,
                                                        float* __restrict__ out) {
    __shared__ __align__(16) u16 Ks[64*32];
    __shared__ __align__(16) u16 Vt[32*64];
    const int bx = blockIdx.x;
    const int qt = bx & 7, h = (bx >> 3) & 7, b = bx >> 6;
    const int tid = threadIdx.x;
    const int w = tid >> 6, lane = tid & 63;
    const int lr = lane & 15, lg = lane >> 4;
    const int m0 = qt*128 + w*32;
    const float scale = 0.1767766952966369f;

    short8 qf[2];
    #pragma unroll
    for (int j = 0; j < 2; ++j) {
        int lq = m0 + j*16 + lr; if (lq > LQ-1) lq = LQ-1;
        const float* qp = &qk[((size_t)lq*BSZ + b)*QKS + h*DH + lg*8];
        float4 a = *reinterpret_cast<const float4*>(qp);
        float4 c = *reinterpret_cast<const float4*>(qp + 4);
        u16 t[8] = { f2bf(a.x*scale), f2bf(a.y*scale), f2bf(a.z*scale), f2bf(a.w*scale),
                     f2bf(c.x*scale), f2bf(c.y*scale), f2bf(c.z*scale), f2bf(c.w*scale) };
        qf[j] = *reinterpret_cast<short8*>(t);
    }

    f32x4 o00 = {}, o01 = {}, o10 = {}, o11 = {};
    float m[2] = {-1e30f, -1e30f}, l[2] = {0.f, 0.f};
    const f32x4 zero = {};

    for (int kt = 0; kt < 15; ++kt) {
        __syncthreads();
        {
            const int key = tid >> 2, c = tid & 3;
            int kg = kt*64 + key; if (kg > LQ-1) kg = LQ-1;
            const size_t kbase = ((size_t)kg*BSZ + b)*QKS + 256 + h*DH + c*8;
            const size_t vbase = ((size_t)kg*BSZ + b)*CDIM + h*DH + c*8;
            float4 k0 = *reinterpret_cast<const float4*>(&qk[kbase]);
            float4 k1 = *reinterpret_cast<const float4*>(&qk[kbase+4]);
            float4 v0 = *reinterpret_cast<const float4*>(&v[vbase]);
            float4 v1 = *reinterpret_cast<const float4*>(&v[vbase+4]);
            u16 kb[8] = { f2bf(k0.x), f2bf(k0.y), f2bf(k0.z), f2bf(k0.w),
                          f2bf(k1.x), f2bf(k1.y), f2bf(k1.z), f2bf(k1.w) };
            *reinterpret_cast<short8*>(&Ks[key*32 + ((c ^ ((key>>1)&3)) * 8)]) =
                *reinterpret_cast<short8*>(kb);
            float vv[8] = { v0.x, v0.y, v0.z, v0.w, v1.x, v1.y, v1.z, v1.w };
            #pragma unroll
            for (int e = 0; e < 8; ++e) {
                const int dh = c*8 + e;
                Vt[dh*64 + (((key>>3) ^ (dh&7)) * 8) + (key&7)] = f2bf(vv[e]);
            }
        }
        __syncthreads();

        f32x4 s[4][2];
        #pragma unroll
        for (int i = 0; i < 4; ++i) {
            const int key = i*16 + lr;
            short8 kf = *reinterpret_cast<const short8*>(&Ks[key*32 + ((lg ^ ((key>>1)&3)) * 8)]);
            s[i][0] = __builtin_amdgcn_mfma_f32_16x16x32_bf16(kf, qf[0], zero, 0, 0, 0);
            s[i][1] = __builtin_amdgcn_mfma_f32_16x16x32_bf16(kf, qf[1], zero, 0, 0, 0);
        }
        const int lim = LQ - kt*64 - lg*4;
        #pragma unroll
        for (int i = 0; i < 4; ++i)
            #pragma unroll
            for (int r = 0; r < 4; ++r)
                if (i*16 + r >= lim) { s[i][0][r] = -1e30f; s[i][1][r] = -1e30f; }

        #pragma unroll
        for (int j = 0; j < 2; ++j) {
            float mx = -1e30f;
            #pragma unroll
            for (int i = 0; i < 4; ++i)
                #pragma unroll
                for (int r = 0; r < 4; ++r) mx = fmaxf(mx, s[i][j][r]);
            mx = fmaxf(mx, __shfl_xor(mx, 16));
            mx = fmaxf(mx, __shfl_xor(mx, 32));
            const float mn = fmaxf(m[j], mx);
            const float corr = __expf(m[j] - mn);
            float sum = 0.f;
            #pragma unroll
            for (int i = 0; i < 4; ++i)
                #pragma unroll
                for (int r = 0; r < 4; ++r) {
                    float p = __expf(s[i][j][r] - mn);
                    s[i][j][r] = p;
                    sum += p;
                }
            sum += __shfl_xor(sum, 16);
            sum += __shfl_xor(sum, 32);
            l[j] = l[j]*corr + sum;
            m[j] = mn;
            if (j == 0) { o00 *= corr; o10 *= corr; }
            else        { o01 *= corr; o11 *= corr; }
        }

        short8 pb[2][2];
        #pragma unroll
        for (int kh = 0; kh < 2; ++kh)
            #pragma unroll
            for (int j = 0; j < 2; ++j) {
                u16 t[8];
                #pragma unroll
                for (int e = 0; e < 4; ++e) {
                    t[e]   = f2bf(s[2*kh][j][e]);
                    t[e+4] = f2bf(s[2*kh+1][j][e]);
                }
                pb[kh][j] = *reinterpret_cast<short8*>(t);
            }

        #pragma unroll
        for (int ip = 0; ip < 2; ++ip) {
            const int dh = ip*16 + lr;
            #pragma unroll
            for (int kh = 0; kh < 2; ++kh) {
                u16 t[8];
                const int c0 = (kh*4 + (lg>>1)) ^ (dh&7);
                const int c1 = (kh*4 + 2 + (lg>>1)) ^ (dh&7);
                *reinterpret_cast<uint2*>(&t[0]) =
                    *reinterpret_cast<const uint2*>(&Vt[dh*64 + c0*8 + (lg&1)*4]);
                *reinterpret_cast<uint2*>(&t[4]) =
                    *reinterpret_cast<const uint2*>(&Vt[dh*64 + c1*8 + (lg&1)*4]);
                short8 vf = *reinterpret_cast<short8*>(t);
                if (ip == 0) {
                    o00 = __builtin_amdgcn_mfma_f32_16x16x32_bf16(vf, pb[kh][0], o00, 0, 0, 0);
                    o01 = __builtin_amdgcn_mfma_f32_16x16x32_bf16(vf, pb[kh][1], o01, 0, 0, 0);
                } else {
                    o10 = __builtin_amdgcn_mfma_f32_16x16x32_bf16(vf, pb[kh][0], o10, 0, 0, 0);
                    o11 = __builtin_amdgcn_mfma_f32_16x16x32_bf16(vf, pb[kh][1], o11, 0, 0, 0);
                }
            }
        }
    }

    #pragma unroll
    for (int j = 0; j < 2; ++j) {
        const int lq = m0 + j*16 + lr;
        if (lq >= LQ) continue;
        const float inv = 1.f / l[j];
        float* op = &out[((size_t)lq*BSZ + b)*CDIM + h*DH];
        #pragma unroll
        for (int r = 0; r < 4; ++r) {
            const f32x4& a0 = (j == 0) ? o00 : o01;
            const f32x4& a1 = (j == 0) ? o10 : o11;
            op[lg*4 + r]      = a0[r] * inv;
            op[16 + lg*4 + r] = a1[r] * inv;
        }
    }
}

// ---------------- fused residual + LayerNorm ----------------
__global__ __launch_bounds__(256) void ln_res_kernel(const float* __restrict__ xin,
                                                     const float* __restrict__ res,
                                                     const float* __restrict__ g,
                                                     const float* __restrict__ beta,
                                                     float* __restrict__ out) {
    const int row  = blockIdx.x * 4 + (threadIdx.x >> 6);
    const int lane = threadIdx.x & 63;
    const size_t base = (size_t)row * CDIM + lane * 4;
    float4 a = *reinterpret_cast<const float4*>(&xin[base]);
    float4 r = *reinterpret_cast<const float4*>(&res[base]);
    float x0 = a.x+r.x, x1 = a.y+r.y, x2 = a.z+r.z, x3 = a.w+r.w;
    float s = x0+x1+x2+x3;
    #pragma unroll
    for (int o = 1; o < 64; o <<= 1) s += __shfl_xor(s, o);
    float mean = s * (1.f/256.f);
    float d0 = x0-mean, d1 = x1-mean, d2 = x2-mean, d3 = x3-mean;
    float sq = d0*d0 + d1*d1 + d2*d2 + d3*d3;
    #pragma unroll
    for (int o = 1; o < 64; o <<= 1) sq += __shfl_xor(sq, o);
    float rs = rsqrtf(sq * (1.f/256.f) + 1e-5f);
    float4 gg = *reinterpret_cast<const float4*>(&g[lane*4]);
    float4 bb = *reinterpret_cast<const float4*>(&beta[lane*4]);
    float4 o4 = make_float4(d0*rs*gg.x+bb.x, d1*rs*gg.y+bb.y, d2*rs*gg.z+bb.z, d3*rs*gg.w+bb.w);
    *reinterpret_cast<float4*>(&out[base]) = o4;
}

// ---------------- softmax over 20 (in merged oab buffer, offset 320) ----------------
__global__ __launch_bounds__(256) void softmax20_kernel(float* __restrict__ oab) {
    int item = blockIdx.x * 256 + threadIdx.x;
    if (item >= ROWS * NH) return;
    int row = item >> 3, h = item & 7;
    float* p = &oab[(size_t)row*OAS + 320 + h*20];
    float mx = -1e30f;
    float e[20];
    #pragma unroll
    for (int j = 0; j < 20; ++j) mx = fmaxf(mx, p[j]);
    float sum = 0.f;
    #pragma unroll
    for (int j = 0; j < 20; ++j) { e[j] = __expf(p[j] - mx); sum += e[j]; }
    float inv = 1.f / sum;
    #pragma unroll
    for (int j = 0; j < 20; ++j) p[j] = e[j] * inv;
}

// ---------------- ms-deformable sampling ----------------
__global__ __launch_bounds__(256) void msdeform_kernel(const __hip_bfloat16* __restrict__ value,
                                                       const float* __restrict__ oab,
                                                       const float* __restrict__ refp,
                                                       float* __restrict__ samp) {
    const int gid = blockIdx.x * 8 + (threadIdx.x >> 5);
    const int d   = threadIdx.x & 31;
    const int h   = gid & 7;
    const int row = gid >> 3;
    const int b   = row & 7;
    const int HL[5] = {128, 64, 32, 16, 8};
    const int WL[5] = {128, 64, 32, 16, 8};
    const int SL[5] = {0, 16384, 20480, 21504, 21760};
    float acc = 0.f;
    #pragma unroll
    for (int l = 0; l < 5; ++l) {
        const float rx = refp[((size_t)row*5 + l)*2 + 0];
        const float ry = refp[((size_t)row*5 + l)*2 + 1];
        const float Wf = (float)WL[l], Hf = (float)HL[l];
        #pragma unroll
        for (int p = 0; p < 4; ++p) {
            const int oc = ((h*5 + l)*4 + p)*2;
            const float ox = oab[(size_t)row*OAS + oc];
            const float oy = oab[(size_t)row*OAS + oc + 1];
            const float a  = oab[(size_t)row*OAS + 320 + h*20 + l*4 + p];
            const float x = (rx + ox / Wf) * Wf - 0.5f;
            const float y = (ry + oy / Hf) * Hf - 0.5f;
            const float x0f = floorf(x), y0f = floorf(y);
            const float fx = x - x0f, fy = y - y0f;
            const int x0 = (int)x0f, y0 = (int)y0f;
            const float w00 = (1.f-fx)*(1.f-fy), w10 = fx*(1.f-fy);
            const float w01 = (1.f-fx)*fy,       w11 = fx*fy;
            #pragma unroll
            for (int c = 0; c < 4; ++c) {
                const int dx = c & 1, dy = c >> 1;
                const int xc = x0 + dx, yc = y0 + dy;
                if (xc >= 0 && xc < WL[l] && yc >= 0 && yc < HL[l]) {
                    const float w = (c==0) ? w00 : (c==1) ? w10 : (c==2) ? w01 : w11;
                    const size_t vrow = (size_t)(SL[l] + yc*WL[l] + xc)*BSZ + b;
                    float vv = __bfloat162float(value[vrow*CDIM + h*DH + d]);
                    acc += a * w * vv;
                }
            }
        }
    }
    samp[(size_t)row*CDIM + h*DH + d] = acc;
}

// ---------------- launch ----------------
extern "C" void kernel_launch(void* const* d_in, const int* in_sizes, int n_in,
                              void* d_out, int out_size, void* d_ws, size_t ws_size,
                              hipStream_t stream) {
    (void)in_sizes; (void)n_in; (void)out_size; (void)ws_size;
    const float* tgt    = (const float*)d_in[0];
    const float* qpos   = (const float*)d_in[1];
    const float* refpts = (const float*)d_in[2];
    const float* memory = (const float*)d_in[3];
    const float* Wq  = (const float*)d_in[6];
    const float* Wk  = (const float*)d_in[7];
    const float* Wv  = (const float*)d_in[8];
    const float* Wo  = (const float*)d_in[9];
    const float* Woff= (const float*)d_in[10];
    const float* Watt= (const float*)d_in[11];
    const float* Wval= (const float*)d_in[12];
    const float* Wout= (const float*)d_in[13];
    const float* W1  = (const float*)d_in[14];
    const float* W2  = (const float*)d_in[15];
    const float* bq  = (const float*)d_in[16];
    const float* bk  = (const float*)d_in[17];
    const float* bv  = (const float*)d_in[18];
    const float* bo  = (const float*)d_in[19];
    const float* boff= (const float*)d_in[20];
    const float* batt= (const float*)d_in[21];
    const float* bval= (const float*)d_in[22];
    const float* bout= (const float*)d_in[23];
    const float* b1  = (const float*)d_in[24];
    const float* b2  = (const float*)d_in[25];
    const float* ln1g= (const float*)d_in[26];
    const float* ln1b= (const float*)d_in[27];
    const float* ln2g= (const float*)d_in[28];
    const float* ln2b= (const float*)d_in[29];
    const float* ln3g= (const float*)d_in[30];
    const float* ln3b= (const float*)d_in[31];
    float* out = (float*)d_out;

    char* ws = (char*)d_ws;
    const size_t RB = (size_t)ROWS * CDIM * 4;     // 7.37 MB
    float* tgt2  = (float*)(ws + 0*RB);
    float* tgt3  = (float*)(ws + 1*RB);
    float* qk    = (float*)(ws + 2*RB);            // qk-in / sa-o / ca-o
    float* vbuf  = (float*)(ws + 3*RB);            // v / samp
    float* abuf  = (float*)(ws + 4*RB);            // attn-out / qb / ffn-out
    float* qkbuf = (float*)(ws + 5*RB);                        // 7200x512
    float* oab   = (float*)(ws + 5*RB + (size_t)ROWS*QKS*4);   // 7200x480
    char*  wsm   = ws + 5*RB + (size_t)ROWS*QKS*4 + (size_t)ROWS*OAS*4;
    u16* WqkT  = (u16*)(wsm);                       // 512x256
    u16* WvT   = (u16*)(wsm + 262144);              // 256x256
    u16* WoT   = (u16*)(wsm + 262144 + 1*131072);
    u16* WvalT = (u16*)(wsm + 262144 + 2*131072);
    u16* WoutT = (u16*)(wsm + 262144 + 3*131072);
    u16* WoaT  = (u16*)(wsm + 262144 + 4*131072);   // 512x256 (480 used, padded)
    float* bqk = (float*)(wsm + 2*262144 + 4*131072);           // 512
    float* boa = (float*)(wsm + 2*262144 + 4*131072 + 2048);    // 480
    char* big  = wsm + 2*262144 + 4*131072 + 4096;
    u16* valb  = (u16*)big;                         // 174592x256 bf16 (89 MB)
    u16* W1T   = (u16*)big;                         // reuse after msdeform
    u16* W2T   = (u16*)(big + 1048576);
    u16* ffnh  = (u16*)(big + 2097152);             // 7200x2048 bf16

    const int n4 = ROWS * CDIM / 4;
    const dim3 blk(256);

    // ---- weight prep ----
    Wt6 wargs = { Wq, Wk, Wv, Wo, Wval, Wout,
                  WqkT, WqkT + 256*256, WvT, WoT, WvalT, WoutT };
    wt6_kernel<<<dim3(8,8,6), blk, 0, stream>>>(wargs);
    wt_kernel<<<dim3(10,8), blk, 0, stream>>>(Woff, WoaT, CDIM, 320);
    wt_kernel<<<dim3(5,8),  blk, 0, stream>>>(Watt, WoaT + 320*256, CDIM, 160);
    biascat_kernel<<<dim3(4), blk, 0, stream>>>(bq, bk, bqk, boff, batt, boa);

    // ---- stage 1: self-attention ----
    addvec_kernel<<<dim3((n4+255)/256), blk, 0, stream>>>(tgt, qpos, qk, n4);
    gemm_mfma<float,0,float><<<dim3(4,57), blk, 0, stream>>>(qk,  WqkT, bqk, qkbuf, ROWS, QKS, CDIM);
    gemm_mfma<float,0,float><<<dim3(2,57), blk, 0, stream>>>(tgt, WvT,  bv,  vbuf,  ROWS, CDIM, CDIM);
    attn_mfma_kernel<<<dim3(512), blk, 0, stream>>>(qkbuf, vbuf, abuf);
    gemm_mfma<float,0,float><<<dim3(2,57), blk, 0, stream>>>(abuf, WoT, bo, qk, ROWS, CDIM, CDIM);
    ln_res_kernel<<<dim3(ROWS/4), blk, 0, stream>>>(qk, tgt, ln2g, ln2b, tgt2);

    // ---- stage 2: deformable cross-attention ----
    gemm_mfma<float,0,u16><<<dim3(2,1364), blk, 0, stream>>>(memory, WvalT, bval, valb, VROWS, CDIM, CDIM);
    addvec_kernel<<<dim3((n4+255)/256), blk, 0, stream>>>(tgt2, qpos, abuf, n4);
    gemm_mfma<float,0,float><<<dim3(4,57), blk, 0, stream>>>(abuf, WoaT, boa, oab, ROWS, OAS, CDIM);
    softmax20_kernel<<<dim3((ROWS*NH+255)/256), blk, 0, stream>>>(oab);
    msdeform_kernel<<<dim3(ROWS), blk, 0, stream>>>((const __hip_bfloat16*)valb, oab, refpts, vbuf);
    gemm_mfma<float,0,float><<<dim3(2,57), blk, 0, stream>>>(vbuf, WoutT, bout, qk, ROWS, CDIM, CDIM);
    ln_res_kernel<<<dim3(ROWS/4), blk, 0, stream>>>(qk, tgt2, ln1g, ln1b, tgt3);

    // ---- stage 3: FFN (W1T/W2T/ffnh alias the dead valb region) ----
    wt_kernel<<<dim3(64,8), blk, 0, stream>>>(W1, W1T, CDIM, DFF);
    wt_kernel<<<dim3(8,64), blk, 0, stream>>>(W2, W2T, DFF, CDIM);
    gemm_mfma<float,1,u16><<<dim3(16,57), blk, 0, stream>>>(tgt3, W1T, b1, ffnh, ROWS, DFF, CDIM);
    gemm_mfma<u16,0,float><<<dim3(2,57),  blk, 0, stream>>>(ffnh, W2T, b2, abuf, ROWS, CDIM, DFF);
    ln_res_kernel<<<dim3(ROWS/4), blk, 0, stream>>>(abuf, tgt3, ln3g, ln3b, out);
}

// Round 6
// 420.378 us; speedup vs baseline: 2.7739x; 1.0612x over previous
//
#include <hip/hip_runtime.h>
#include <hip/hip_bf16.h>
#include <type_traits>

#define LQ    900
#define BSZ   8
#define ROWS  (LQ*BSZ)        // 7200
#define CDIM  256
#define QKS   512             // merged q|k row stride
#define OAS   480             // merged off|aw row stride
#define NH    8
#define DH    32
#define LVTOT 21824
#define VROWS (LVTOT*BSZ)     // 174592
#define DFF   2048

typedef unsigned short u16;
typedef short short8 __attribute__((ext_vector_type(8)));
typedef float f32x4 __attribute__((ext_vector_type(4)));

__device__ __forceinline__ u16 f2bf(float f) {
    __hip_bfloat16 h = __float2bfloat16(f);
    return *reinterpret_cast<u16*>(&h);
}

// ---------------- elementwise add (float4) ----------------
__global__ __launch_bounds__(256) void addvec_kernel(const float* __restrict__ a,
                                                     const float* __restrict__ b,
                                                     float* __restrict__ c, int n4) {
    int i = blockIdx.x * 256 + threadIdx.x;
    if (i < n4) {
        float4 x = reinterpret_cast<const float4*>(a)[i];
        float4 y = reinterpret_cast<const float4*>(b)[i];
        reinterpret_cast<float4*>(c)[i] = make_float4(x.x+y.x, x.y+y.y, x.z+y.z, x.w+y.w);
    }
}

// ---------------- weight transpose + cvt: W[K][N] f32 -> Wt[N][K] bf16 ----------------
__global__ __launch_bounds__(256) void wt_kernel(const float* __restrict__ W, u16* __restrict__ Wt,
                                                 int K, int N) {
    __shared__ float t[32][33];
    const int n0 = blockIdx.x * 32, k0 = blockIdx.y * 32;
    const int tx = threadIdx.x & 31, ty = threadIdx.x >> 5;
    #pragma unroll
    for (int r = ty; r < 32; r += 8)
        t[r][tx] = W[(size_t)(k0 + r) * N + n0 + tx];
    __syncthreads();
    #pragma unroll
    for (int r = ty; r < 32; r += 8)
        Wt[(size_t)(n0 + r) * K + k0 + tx] = f2bf(t[tx][r]);
}

// six 256x256 transposes in one dispatch
struct Wt6 { const float* s0; const float* s1; const float* s2; const float* s3; const float* s4; const float* s5;
             u16* d0; u16* d1; u16* d2; u16* d3; u16* d4; u16* d5; };
__global__ __launch_bounds__(256) void wt6_kernel(Wt6 a) {
    __shared__ float t[32][33];
    const float* W; u16* Wt;
    switch (blockIdx.z) {
        case 0: W = a.s0; Wt = a.d0; break;
        case 1: W = a.s1; Wt = a.d1; break;
        case 2: W = a.s2; Wt = a.d2; break;
        case 3: W = a.s3; Wt = a.d3; break;
        case 4: W = a.s4; Wt = a.d4; break;
        default: W = a.s5; Wt = a.d5; break;
    }
    const int n0 = blockIdx.x * 32, k0 = blockIdx.y * 32;
    const int tx = threadIdx.x & 31, ty = threadIdx.x >> 5;
    #pragma unroll
    for (int r = ty; r < 32; r += 8)
        t[r][tx] = W[(size_t)(k0 + r) * 256 + n0 + tx];
    __syncthreads();
    #pragma unroll
    for (int r = ty; r < 32; r += 8)
        Wt[(size_t)(n0 + r) * 256 + k0 + tx] = f2bf(t[tx][r]);
}

// bias concat: bqk = [bq|bk] (512), boa = [boff|batt] (480)
__global__ __launch_bounds__(256) void biascat_kernel(const float* bq, const float* bk, float* bqk,
                                                      const float* boff, const float* batt, float* boa) {
    int t = blockIdx.x * 256 + threadIdx.x;
    if (t < 256) bqk[t] = bq[t];
    else if (t < 512) bqk[t] = bk[t - 256];
    else if (t < 832) boa[t - 512] = boff[t - 512];
    else if (t < 992) boa[t - 832 + 320] = batt[t - 832];
}

// ---------------- staging helpers ----------------
__device__ __forceinline__ void stage_B(const u16* __restrict__ Wt, u16* bsb,
                                        int n0, int k0, int K, int tid) {
    #pragma unroll
    for (int i = 0; i < 4; ++i) {
        const int gi = i*256 + tid;
        const int row = gi >> 3, c = gi & 7;
        const u16* gsrc = Wt + (size_t)(n0 + row) * K + k0 + ((c ^ (row & 7)) << 3);
        u16* ldst = bsb + ((i*256 + (tid & 192)) << 3);
        __builtin_amdgcn_global_load_lds((const __attribute__((address_space(1))) void*)gsrc,
                                         (__attribute__((address_space(3))) void*)ldst, 16, 0, 0);
    }
}

__device__ __forceinline__ void stage_A_bf16(const u16* __restrict__ A, u16* bsa,
                                             int M, int K, int m0, int k0, int tid) {
    #pragma unroll
    for (int i = 0; i < 4; ++i) {
        const int gi = i*256 + tid;
        const int row = gi >> 3, c = gi & 7;
        int grow = m0 + row; if (grow >= M) grow = M - 1;
        const u16* gsrc = A + (size_t)grow * K + k0 + ((c ^ (row & 7)) << 3);
        u16* ldst = bsa + ((i*256 + (tid & 192)) << 3);
        __builtin_amdgcn_global_load_lds((const __attribute__((address_space(1))) void*)gsrc,
                                         (__attribute__((address_space(3))) void*)ldst, 16, 0, 0);
    }
}

__device__ __forceinline__ void load_A_f32(float* areg, const float* __restrict__ A,
                                           int M, int K, int m0, int k0, int tid) {
    const int sr = tid >> 1, sc = (tid & 1) * 4;
    const int grow = m0 + sr;
    if (grow < M) {
        const float4* src = reinterpret_cast<const float4*>(&A[(size_t)grow * K + k0 + sc * 8]);
        #pragma unroll
        for (int i = 0; i < 8; ++i)
            *reinterpret_cast<float4*>(&areg[i*4]) = src[i];
    } else {
        #pragma unroll
        for (int i = 0; i < 32; ++i) areg[i] = 0.f;
    }
}

__device__ __forceinline__ void write_A(u16* bsa, const float* areg, int tid) {
    const int sr = tid >> 1, sc = (tid & 1) * 4;
    u16 tmp[32];
    #pragma unroll
    for (int i = 0; i < 32; ++i) tmp[i] = f2bf(areg[i]);
    #pragma unroll
    for (int c4 = 0; c4 < 4; ++c4) {
        const int c = sc + c4;
        *reinterpret_cast<uint4*>(&bsa[sr*64 + ((c ^ (sr & 7)) * 8)]) =
            *reinterpret_cast<const uint4*>(&tmp[c4*8]);
    }
}

// ---------------- bf16 MFMA GEMM: C = A @ Wt^T + bias ----------------
template<typename AT, int RELU, typename OutT>
__global__ __launch_bounds__(256) void gemm_mfma(const AT* __restrict__ A,
                                                 const u16* __restrict__ Wt,
                                                 const float* __restrict__ bias,
                                                 OutT* __restrict__ C,
                                                 int M, int N, int K) {
    __shared__ __align__(16) u16 As[2][128*64];
    __shared__ __align__(16) u16 Bs[2][128*64];
    const int tid = threadIdx.x;
    const int m0 = blockIdx.y * 128, n0 = blockIdx.x * 128;
    const int lane = tid & 63;
    const int wr = (tid >> 7) & 1, wc = (tid >> 6) & 1;
    const int lr = lane & 15, lg = lane >> 4;
    const int nsteps = K >> 6;

    f32x4 acc[4][4] = {};
    float areg[32];

    stage_B(Wt, Bs[0], n0, 0, K, tid);
    if constexpr (std::is_same<AT, float>::value) {
        load_A_f32(areg, A, M, K, m0, 0, tid);
        write_A(As[0], areg, tid);
    } else {
        stage_A_bf16((const u16*)A, As[0], M, K, m0, 0, tid);
    }
    __syncthreads();

    for (int t = 0; t < nsteps; ++t) {
        const int cur = t & 1;
        if (t + 1 < nsteps) {
            stage_B(Wt, Bs[cur ^ 1], n0, (t+1) << 6, K, tid);
            if constexpr (std::is_same<AT, float>::value)
                load_A_f32(areg, A, M, K, m0, (t+1) << 6, tid);
            else
                stage_A_bf16((const u16*)A, As[cur ^ 1], M, K, m0, (t+1) << 6, tid);
        }
        #pragma unroll
        for (int h = 0; h < 2; ++h) {
            short8 af[4], bfr[4];
            #pragma unroll
            for (int i = 0; i < 4; ++i) {
                const int r = wr*64 + i*16 + lr;
                af[i] = *reinterpret_cast<const short8*>(&As[cur][r*64 + (((h*4 + lg) ^ (r & 7)) * 8)]);
            }
            #pragma unroll
            for (int j = 0; j < 4; ++j) {
                const int r = wc*64 + j*16 + lr;
                bfr[j] = *reinterpret_cast<const short8*>(&Bs[cur][r*64 + (((h*4 + lg) ^ (r & 7)) * 8)]);
            }
            #pragma unroll
            for (int i = 0; i < 4; ++i)
                #pragma unroll
                for (int j = 0; j < 4; ++j)
                    acc[i][j] = __builtin_amdgcn_mfma_f32_16x16x32_bf16(af[i], bfr[j], acc[i][j], 0, 0, 0);
        }
        if (t + 1 < nsteps) {
            if constexpr (std::is_same<AT, float>::value)
                write_A(As[cur ^ 1], areg, tid);
        }
        __syncthreads();
    }

    if constexpr (std::is_same<OutT, float>::value) {
        #pragma unroll
        for (int j = 0; j < 4; ++j) {
            const int col = n0 + wc*64 + j*16 + lr;
            if (col >= N) continue;
            const float bcol = bias[col];
            #pragma unroll
            for (int i = 0; i < 4; ++i) {
                #pragma unroll
                for (int r = 0; r < 4; ++r) {
                    const int row = m0 + wr*64 + i*16 + lg*4 + r;
                    if (row >= M) continue;
                    float v = acc[i][j][r] + bcol;
                    if (RELU) v = fmaxf(v, 0.f);
                    C[(size_t)row * N + col] = v;
                }
            }
        }
    } else {
        u16* Ct = &As[0][0];
        #pragma unroll
        for (int j = 0; j < 4; ++j) {
            const int col = wc*64 + j*16 + lr;
            const float bcol = bias[n0 + col];
            #pragma unroll
            for (int i = 0; i < 4; ++i)
                #pragma unroll
                for (int r = 0; r < 4; ++r) {
                    float v = acc[i][j][r] + bcol;
                    if (RELU) v = fmaxf(v, 0.f);
                    Ct[(wr*64 + i*16 + lg*4 + r)*128 + col] = f2bf(v);
                }
        }
        __syncthreads();
        #pragma unroll
        for (int it = 0; it < 8; ++it) {
            const int idx = it*256 + tid;
            const int row = idx >> 4, cc = idx & 15;
            if (m0 + row < M)
                *reinterpret_cast<uint4*>(&C[(size_t)(m0 + row) * N + n0 + cc*8]) =
                    *reinterpret_cast<const uint4*>(&Ct[row*128 + cc*8]);
        }
    }
}

// ---------------- MFMA flash self-attention ----------------
__global__ __launch_bounds__(256) void attn_mfma_kernel(const float* __restrict__ qk,
                                                        const float* __restrict__ v,
                                                        float* __restrict__ out) {
    __shared__ __align__(16) u16 Ks[64*32];
    __shared__ __align__(16) u16 Vt[32*64];
    const int bx = blockIdx.x;
    const int qt = bx & 7, h = (bx >> 3) & 7, b = bx >> 6;
    const int tid = threadIdx.x;
    const int w = tid >> 6, lane = tid & 63;
    const int lr = lane & 15, lg = lane >> 4;
    const int m0 = qt*128 + w*32;
    const float scale = 0.1767766952966369f;

    short8 qf[2];
    #pragma unroll
    for (int j = 0; j < 2; ++j) {
        int lq = m0 + j*16 + lr; if (lq > LQ-1) lq = LQ-1;
        const float* qp = &qk[((size_t)lq*BSZ + b)*QKS + h*DH + lg*8];
        float4 a = *reinterpret_cast<const float4*>(qp);
        float4 c = *reinterpret_cast<const float4*>(qp + 4);
        u16 t[8] = { f2bf(a.x*scale), f2bf(a.y*scale), f2bf(a.z*scale), f2bf(a.w*scale),
                     f2bf(c.x*scale), f2bf(c.y*scale), f2bf(c.z*scale), f2bf(c.w*scale) };
        qf[j] = *reinterpret_cast<short8*>(t);
    }

    f32x4 o00 = {}, o01 = {}, o10 = {}, o11 = {};
    float m[2] = {-1e30f, -1e30f}, l[2] = {0.f, 0.f};
    const f32x4 zero = {};

    for (int kt = 0; kt < 15; ++kt) {
        __syncthreads();
        {
            const int key = tid >> 2, c = tid & 3;
            int kg = kt*64 + key; if (kg > LQ-1) kg = LQ-1;
            const size_t kbase = ((size_t)kg*BSZ + b)*QKS + 256 + h*DH + c*8;
            const size_t vbase = ((size_t)kg*BSZ + b)*CDIM + h*DH + c*8;
            float4 k0 = *reinterpret_cast<const float4*>(&qk[kbase]);
            float4 k1 = *reinterpret_cast<const float4*>(&qk[kbase+4]);
            float4 v0 = *reinterpret_cast<const float4*>(&v[vbase]);
            float4 v1 = *reinterpret_cast<const float4*>(&v[vbase+4]);
            u16 kb[8] = { f2bf(k0.x), f2bf(k0.y), f2bf(k0.z), f2bf(k0.w),
                          f2bf(k1.x), f2bf(k1.y), f2bf(k1.z), f2bf(k1.w) };
            *reinterpret_cast<short8*>(&Ks[key*32 + ((c ^ ((key>>1)&3)) * 8)]) =
                *reinterpret_cast<short8*>(kb);
            float vv[8] = { v0.x, v0.y, v0.z, v0.w, v1.x, v1.y, v1.z, v1.w };
            #pragma unroll
            for (int e = 0; e < 8; ++e) {
                const int dh = c*8 + e;
                Vt[dh*64 + (((key>>3) ^ (dh&7)) * 8) + (key&7)] = f2bf(vv[e]);
            }
        }
        __syncthreads();

        f32x4 s[4][2];
        #pragma unroll
        for (int i = 0; i < 4; ++i) {
            const int key = i*16 + lr;
            short8 kf = *reinterpret_cast<const short8*>(&Ks[key*32 + ((lg ^ ((key>>1)&3)) * 8)]);
            s[i][0] = __builtin_amdgcn_mfma_f32_16x16x32_bf16(kf, qf[0], zero, 0, 0, 0);
            s[i][1] = __builtin_amdgcn_mfma_f32_16x16x32_bf16(kf, qf[1], zero, 0, 0, 0);
        }
        const int lim = LQ - kt*64 - lg*4;
        #pragma unroll
        for (int i = 0; i < 4; ++i)
            #pragma unroll
            for (int r = 0; r < 4; ++r)
                if (i*16 + r >= lim) { s[i][0][r] = -1e30f; s[i][1][r] = -1e30f; }

        #pragma unroll
        for (int j = 0; j < 2; ++j) {
            float mx = -1e30f;
            #pragma unroll
            for (int i = 0; i < 4; ++i)
                #pragma unroll
                for (int r = 0; r < 4; ++r) mx = fmaxf(mx, s[i][j][r]);
            mx = fmaxf(mx, __shfl_xor(mx, 16));
            mx = fmaxf(mx, __shfl_xor(mx, 32));
            const float mn = fmaxf(m[j], mx);
            const float corr = __expf(m[j] - mn);
            float sum = 0.f;
            #pragma unroll
            for (int i = 0; i < 4; ++i)
                #pragma unroll
                for (int r = 0; r < 4; ++r) {
                    float p = __expf(s[i][j][r] - mn);
                    s[i][j][r] = p;
                    sum += p;
                }
            sum += __shfl_xor(sum, 16);
            sum += __shfl_xor(sum, 32);
            l[j] = l[j]*corr + sum;
            m[j] = mn;
            if (j == 0) { o00 *= corr; o10 *= corr; }
            else        { o01 *= corr; o11 *= corr; }
        }

        short8 pb[2][2];
        #pragma unroll
        for (int kh = 0; kh < 2; ++kh)
            #pragma unroll
            for (int j = 0; j < 2; ++j) {
                u16 t[8];
                #pragma unroll
                for (int e = 0; e < 4; ++e) {
                    t[e]   = f2bf(s[2*kh][j][e]);
                    t[e+4] = f2bf(s[2*kh+1][j][e]);
                }
                pb[kh][j] = *reinterpret_cast<short8*>(t);
            }

        #pragma unroll
        for (int ip = 0; ip < 2; ++ip) {
            const int dh = ip*16 + lr;
            #pragma unroll
            for (int kh = 0; kh < 2; ++kh) {
                u16 t[8];
                const int c0 = (kh*4 + (lg>>1)) ^ (dh&7);
                const int c1 = (kh*4 + 2 + (lg>>1)) ^ (dh&7);
                *reinterpret_cast<uint2*>(&t[0]) =
                    *reinterpret_cast<const uint2*>(&Vt[dh*64 + c0*8 + (lg&1)*4]);
                *reinterpret_cast<uint2*>(&t[4]) =
                    *reinterpret_cast<const uint2*>(&Vt[dh*64 + c1*8 + (lg&1)*4]);
                short8 vf = *reinterpret_cast<short8*>(t);
                if (ip == 0) {
                    o00 = __builtin_amdgcn_mfma_f32_16x16x32_bf16(vf, pb[kh][0], o00, 0, 0, 0);
                    o01 = __builtin_amdgcn_mfma_f32_16x16x32_bf16(vf, pb[kh][1], o01, 0, 0, 0);
                } else {
                    o10 = __builtin_amdgcn_mfma_f32_16x16x32_bf16(vf, pb[kh][0], o10, 0, 0, 0);
                    o11 = __builtin_amdgcn_mfma_f32_16x16x32_bf16(vf, pb[kh][1], o11, 0, 0, 0);
                }
            }
        }
    }

    #pragma unroll
    for (int j = 0; j < 2; ++j) {
        const int lq = m0 + j*16 + lr;
        if (lq >= LQ) continue;
        const float inv = 1.f / l[j];
        float* op = &out[((size_t)lq*BSZ + b)*CDIM + h*DH];
        #pragma unroll
        for (int r = 0; r < 4; ++r) {
            const f32x4& a0 = (j == 0) ? o00 : o01;
            const f32x4& a1 = (j == 0) ? o10 : o11;
            op[lg*4 + r]      = a0[r] * inv;
            op[16 + lg*4 + r] = a1[r] * inv;
        }
    }
}

// ---------------- fused residual + LayerNorm ----------------
__global__ __launch_bounds__(256) void ln_res_kernel(const float* __restrict__ xin,
                                                     const float* __restrict__ res,
                                                     const float* __restrict__ g,
                                                     const float* __restrict__ beta,
                                                     float* __restrict__ out) {
    const int row  = blockIdx.x * 4 + (threadIdx.x >> 6);
    const int lane = threadIdx.x & 63;
    const size_t base = (size_t)row * CDIM + lane * 4;
    float4 a = *reinterpret_cast<const float4*>(&xin[base]);
    float4 r = *reinterpret_cast<const float4*>(&res[base]);
    float x0 = a.x+r.x, x1 = a.y+r.y, x2 = a.z+r.z, x3 = a.w+r.w;
    float s = x0+x1+x2+x3;
    #pragma unroll
    for (int o = 1; o < 64; o <<= 1) s += __shfl_xor(s, o);
    float mean = s * (1.f/256.f);
    float d0 = x0-mean, d1 = x1-mean, d2 = x2-mean, d3 = x3-mean;
    float sq = d0*d0 + d1*d1 + d2*d2 + d3*d3;
    #pragma unroll
    for (int o = 1; o < 64; o <<= 1) sq += __shfl_xor(sq, o);
    float rs = rsqrtf(sq * (1.f/256.f) + 1e-5f);
    float4 gg = *reinterpret_cast<const float4*>(&g[lane*4]);
    float4 bb = *reinterpret_cast<const float4*>(&beta[lane*4]);
    float4 o4 = make_float4(d0*rs*gg.x+bb.x, d1*rs*gg.y+bb.y, d2*rs*gg.z+bb.z, d3*rs*gg.w+bb.w);
    *reinterpret_cast<float4*>(&out[base]) = o4;
}

// ---------------- softmax over 20 (in merged oab buffer, offset 320) ----------------
__global__ __launch_bounds__(256) void softmax20_kernel(float* __restrict__ oab) {
    int item = blockIdx.x * 256 + threadIdx.x;
    if (item >= ROWS * NH) return;
    int row = item >> 3, h = item & 7;
    float* p = &oab[(size_t)row*OAS + 320 + h*20];
    float mx = -1e30f;
    float e[20];
    #pragma unroll
    for (int j = 0; j < 20; ++j) mx = fmaxf(mx, p[j]);
    float sum = 0.f;
    #pragma unroll
    for (int j = 0; j < 20; ++j) { e[j] = __expf(p[j] - mx); sum += e[j]; }
    float inv = 1.f / sum;
    #pragma unroll
    for (int j = 0; j < 20; ++j) p[j] = e[j] * inv;
}

// ---------------- ms-deformable sampling ----------------
// 8 lanes per (row,h) group; each lane owns 4 channels (ushort4 gathers).
__global__ __launch_bounds__(256) void msdeform_kernel(const u16* __restrict__ value,
                                                       const float* __restrict__ oab,
                                                       const float* __restrict__ refp,
                                                       float* __restrict__ samp) {
    const int gid = blockIdx.x * 32 + (threadIdx.x >> 3);  // row*8 + h
    const int d4  = threadIdx.x & 3;                        // dummy init (overwritten below)
    const int ch  = (threadIdx.x & 7) * 4;                  // channel base within head
    const int h   = gid & 7;
    const int row = gid >> 3;
    const int b   = row & 7;
    (void)d4;
    const int WL[5] = {128, 64, 32, 16, 8};
    const int SL[5] = {0, 16384, 20480, 21504, 21760};
    const u16* vbase = value + h*DH + ch;
    float a0 = 0.f, a1 = 0.f, a2 = 0.f, a3 = 0.f;
    #pragma unroll
    for (int l = 0; l < 5; ++l) {
        const float2 r2 = *reinterpret_cast<const float2*>(&refp[((size_t)row*5 + l)*2]);
        const int W = WL[l];
        const float Wf = (float)W;
        #pragma unroll
        for (int p = 0; p < 4; ++p) {
            const float2 o2 = *reinterpret_cast<const float2*>(&oab[(size_t)row*OAS + ((h*5 + l)*4 + p)*2]);
            const float aw = oab[(size_t)row*OAS + 320 + h*20 + l*4 + p];
            const float x = (r2.x + o2.x / Wf) * Wf - 0.5f;
            const float y = (r2.y + o2.y / Wf) * Wf - 0.5f;
            const float x0f = floorf(x), y0f = floorf(y);
            const float fx = x - x0f, fy = y - y0f;
            const int x0 = (int)x0f, y0 = (int)y0f;
            float wx0 = (1.f - fx) * aw, wx1 = fx * aw;
            float fy0 = 1.f - fy, fy1 = fy;
            if (x0 < 0 || x0 >= W)       wx0 = 0.f;
            if (x0+1 < 0 || x0+1 >= W)   wx1 = 0.f;
            if (y0 < 0 || y0 >= W)       fy0 = 0.f;
            if (y0+1 < 0 || y0+1 >= W)   fy1 = 0.f;
            const float w00 = wx0*fy0, w10 = wx1*fy0, w01 = wx0*fy1, w11 = wx1*fy1;
            const int xc0 = min(max(x0, 0), W-1),   xc1 = min(max(x0+1, 0), W-1);
            const int yc0 = min(max(y0, 0), W-1),   yc1 = min(max(y0+1, 0), W-1);
            const int r0 = SL[l] + yc0*W, r1 = SL[l] + yc1*W;
            const int o00i = ((r0 + xc0)*BSZ + b) * CDIM;
            const int o10i = ((r0 + xc1)*BSZ + b) * CDIM;
            const int o01i = ((r1 + xc0)*BSZ + b) * CDIM;
            const int o11i = ((r1 + xc1)*BSZ + b) * CDIM;
            const uint2 u00 = *reinterpret_cast<const uint2*>(vbase + o00i);
            const uint2 u10 = *reinterpret_cast<const uint2*>(vbase + o10i);
            const uint2 u01 = *reinterpret_cast<const uint2*>(vbase + o01i);
            const uint2 u11 = *reinterpret_cast<const uint2*>(vbase + o11i);
            a0 += w00 * __uint_as_float(u00.x << 16) + w10 * __uint_as_float(u10.x << 16)
                + w01 * __uint_as_float(u01.x << 16) + w11 * __uint_as_float(u11.x << 16);
            a1 += w00 * __uint_as_float(u00.x & 0xffff0000u) + w10 * __uint_as_float(u10.x & 0xffff0000u)
                + w01 * __uint_as_float(u01.x & 0xffff0000u) + w11 * __uint_as_float(u11.x & 0xffff0000u);
            a2 += w00 * __uint_as_float(u00.y << 16) + w10 * __uint_as_float(u10.y << 16)
                + w01 * __uint_as_float(u01.y << 16) + w11 * __uint_as_float(u11.y << 16);
            a3 += w00 * __uint_as_float(u00.y & 0xffff0000u) + w10 * __uint_as_float(u10.y & 0xffff0000u)
                + w01 * __uint_as_float(u01.y & 0xffff0000u) + w11 * __uint_as_float(u11.y & 0xffff0000u);
        }
    }
    float4 o4 = make_float4(a0, a1, a2, a3);
    *reinterpret_cast<float4*>(&samp[(size_t)row*CDIM + h*DH + ch]) = o4;
}

// ---------------- launch ----------------
extern "C" void kernel_launch(void* const* d_in, const int* in_sizes, int n_in,
                              void* d_out, int out_size, void* d_ws, size_t ws_size,
                              hipStream_t stream) {
    (void)in_sizes; (void)n_in; (void)out_size; (void)ws_size;
    const float* tgt    = (const float*)d_in[0];
    const float* qpos   = (const float*)d_in[1];
    const float* refpts = (const float*)d_in[2];
    const float* memory = (const float*)d_in[3];
    const float* Wq  = (const float*)d_in[6];
    const float* Wk  = (const float*)d_in[7];
    const float* Wv  = (const float*)d_in[8];
    const float* Wo  = (const float*)d_in[9];
    const float* Woff= (const float*)d_in[10];
    const float* Watt= (const float*)d_in[11];
    const float* Wval= (const float*)d_in[12];
    const float* Wout= (const float*)d_in[13];
    const float* W1  = (const float*)d_in[14];
    const float* W2  = (const float*)d_in[15];
    const float* bq  = (const float*)d_in[16];
    const float* bk  = (const float*)d_in[17];
    const float* bv  = (const float*)d_in[18];
    const float* bo  = (const float*)d_in[19];
    const float* boff= (const float*)d_in[20];
    const float* batt= (const float*)d_in[21];
    const float* bval= (const float*)d_in[22];
    const float* bout= (const float*)d_in[23];
    const float* b1  = (const float*)d_in[24];
    const float* b2  = (const float*)d_in[25];
    const float* ln1g= (const float*)d_in[26];
    const float* ln1b= (const float*)d_in[27];
    const float* ln2g= (const float*)d_in[28];
    const float* ln2b= (const float*)d_in[29];
    const float* ln3g= (const float*)d_in[30];
    const float* ln3b= (const float*)d_in[31];
    float* out = (float*)d_out;

    char* ws = (char*)d_ws;
    const size_t RB = (size_t)ROWS * CDIM * 4;     // 7.37 MB
    float* tgt2  = (float*)(ws + 0*RB);
    float* tgt3  = (float*)(ws + 1*RB);
    float* qk    = (float*)(ws + 2*RB);
    float* vbuf  = (float*)(ws + 3*RB);
    float* abuf  = (float*)(ws + 4*RB);
    float* qkbuf = (float*)(ws + 5*RB);                        // 7200x512
    float* oab   = (float*)(ws + 5*RB + (size_t)ROWS*QKS*4);   // 7200x480
    char*  wsm   = ws + 5*RB + (size_t)ROWS*QKS*4 + (size_t)ROWS*OAS*4;
    u16* WqkT  = (u16*)(wsm);
    u16* WvT   = (u16*)(wsm + 262144);
    u16* WoT   = (u16*)(wsm + 262144 + 1*131072);
    u16* WvalT = (u16*)(wsm + 262144 + 2*131072);
    u16* WoutT = (u16*)(wsm + 262144 + 3*131072);
    u16* WoaT  = (u16*)(wsm + 262144 + 4*131072);
    float* bqk = (float*)(wsm + 2*262144 + 4*131072);
    float* boa = (float*)(wsm + 2*262144 + 4*131072 + 2048);
    char* big  = wsm + 2*262144 + 4*131072 + 4096;
    u16* valb  = (u16*)big;                         // 174592x256 bf16 (89 MB)
    u16* W1T   = (u16*)big;
    u16* W2T   = (u16*)(big + 1048576);
    u16* ffnh  = (u16*)(big + 2097152);

    const int n4 = ROWS * CDIM / 4;
    const dim3 blk(256);

    // ---- weight prep ----
    Wt6 wargs = { Wq, Wk, Wv, Wo, Wval, Wout,
                  WqkT, WqkT + 256*256, WvT, WoT, WvalT, WoutT };
    wt6_kernel<<<dim3(8,8,6), blk, 0, stream>>>(wargs);
    wt_kernel<<<dim3(10,8), blk, 0, stream>>>(Woff, WoaT, CDIM, 320);
    wt_kernel<<<dim3(5,8),  blk, 0, stream>>>(Watt, WoaT + 320*256, CDIM, 160);
    biascat_kernel<<<dim3(4), blk, 0, stream>>>(bq, bk, bqk, boff, batt, boa);

    // ---- stage 1: self-attention ----
    addvec_kernel<<<dim3((n4+255)/256), blk, 0, stream>>>(tgt, qpos, qk, n4);
    gemm_mfma<float,0,float><<<dim3(4,57), blk, 0, stream>>>(qk,  WqkT, bqk, qkbuf, ROWS, QKS, CDIM);
    gemm_mfma<float,0,float><<<dim3(2,57), blk, 0, stream>>>(tgt, WvT,  bv,  vbuf,  ROWS, CDIM, CDIM);
    attn_mfma_kernel<<<dim3(512), blk, 0, stream>>>(qkbuf, vbuf, abuf);
    gemm_mfma<float,0,float><<<dim3(2,57), blk, 0, stream>>>(abuf, WoT, bo, qk, ROWS, CDIM, CDIM);
    ln_res_kernel<<<dim3(ROWS/4), blk, 0, stream>>>(qk, tgt, ln2g, ln2b, tgt2);

    // ---- stage 2: deformable cross-attention ----
    gemm_mfma<float,0,u16><<<dim3(2,1364), blk, 0, stream>>>(memory, WvalT, bval, valb, VROWS, CDIM, CDIM);
    addvec_kernel<<<dim3((n4+255)/256), blk, 0, stream>>>(tgt2, qpos, abuf, n4);
    gemm_mfma<float,0,float><<<dim3(4,57), blk, 0, stream>>>(abuf, WoaT, boa, oab, ROWS, OAS, CDIM);
    softmax20_kernel<<<dim3((ROWS*NH+255)/256), blk, 0, stream>>>(oab);
    msdeform_kernel<<<dim3(ROWS*NH/32), blk, 0, stream>>>(valb, oab, refpts, vbuf);
    gemm_mfma<float,0,float><<<dim3(2,57), blk, 0, stream>>>(vbuf, WoutT, bout, qk, ROWS, CDIM, CDIM);
    ln_res_kernel<<<dim3(ROWS/4), blk, 0, stream>>>(qk, tgt2, ln1g, ln1b, tgt3);

    // ---- stage 3: FFN ----
    wt_kernel<<<dim3(64,8), blk, 0, stream>>>(W1, W1T, CDIM, DFF);
    wt_kernel<<<dim3(8,64), blk, 0, stream>>>(W2, W2T, DFF, CDIM);
    gemm_mfma<float,1,u16><<<dim3(16,57), blk, 0, stream>>>(tgt3, W1T, b1, ffnh, ROWS, DFF, CDIM);
    gemm_mfma<u16,0,float><<<dim3(2,57),  blk, 0, stream>>>(ffnh, W2T, b2, abuf, ROWS, CDIM, DFF);
    ln_res_kernel<<<dim3(ROWS/4), blk, 0, stream>>>(abuf, tgt3, ln3g, ln3b, out);
}